// Round 13
// baseline (1456.827 us; speedup 1.0000x reference)
//
#include <hip/hip_runtime.h>

#ifndef BATCH
#define BATCH 16
#endif

typedef float f32x2 __attribute__((ext_vector_type(2)));
__device__ __forceinline__ f32x2 mk2(float a, float b) { f32x2 r; r.x = a; r.y = b; return r; }

// ---- DPP wave64 reduction helpers (row_shr scan + row_bcast merge) --------
template<int CTRL>
__device__ __forceinline__ float dppmaxf(float v)
{
    const int d = __builtin_amdgcn_update_dpp(__float_as_int(v), __float_as_int(v),
                                              CTRL, 0xf, 0xf, false);
    return fmaxf(v, __int_as_float(d));
}
template<int CTRL>
__device__ __forceinline__ unsigned dppminu(unsigned v)
{
    const unsigned d = (unsigned)__builtin_amdgcn_update_dpp((int)v, (int)v,
                                                             CTRL, 0xf, 0xf, false);
    return (d < v) ? d : v;
}
__device__ __forceinline__ float wave_max_bcast(float v)
{
    v = dppmaxf<0x111>(v);
    v = dppmaxf<0x112>(v);
    v = dppmaxf<0x114>(v);
    v = dppmaxf<0x118>(v);
    v = dppmaxf<0x142>(v);
    v = dppmaxf<0x143>(v);
    return __int_as_float(__builtin_amdgcn_readlane(__float_as_int(v), 63));
}
__device__ __forceinline__ unsigned wave_min_bcast(unsigned v)
{
    v = dppminu<0x111>(v);
    v = dppminu<0x112>(v);
    v = dppminu<0x114>(v);
    v = dppminu<0x118>(v);
    v = dppminu<0x142>(v);
    v = dppminu<0x143>(v);
    return (unsigned)__builtin_amdgcn_readlane((int)v, 63);
}

// ---- transpose body: W[O][C] -> Wt[C][O], flat index space ----------------
__device__ __forceinline__ void transpose_body(int blk, int tid,
    const float* __restrict__ s0, float* __restrict__ d0,
    const float* __restrict__ s1, float* __restrict__ d1,
    const float* __restrict__ s2, float* __restrict__ d2,
    const float* __restrict__ s3, float* __restrict__ d3,
    const float* __restrict__ s4, float* __restrict__ d4,
    const float* __restrict__ s5, float* __restrict__ d5,
    const float* __restrict__ s6, float* __restrict__ d6,
    const float* __restrict__ s7, float* __restrict__ d7,
    const float* __restrict__ s8, float* __restrict__ d8)
{
    int i = blk * 256 + tid;
    if (i < 192)    { d0[(i%3)  *64   + i/3  ] = s0[i]; return; }  i -= 192;
    if (i < 4096)   { d1[(i&63) *64   + (i>>6)] = s1[i]; return; } i -= 4096;
    if (i < 8192)   { d2[(i&63) *128  + (i>>6)] = s2[i]; return; } i -= 8192;
    if (i < 16768)  { d3[(i%131)*128  + i/131] = s3[i]; return; }  i -= 16768;
    if (i < 16384)  { d4[(i&127)*128  + (i>>7)] = s4[i]; return; } i -= 16384;
    if (i < 32768)  { d5[(i&127)*256  + (i>>7)] = s5[i]; return; } i -= 32768;
    if (i < 66304)  { d6[(i%259)*256  + i/259] = s6[i]; return; }  i -= 66304;
    if (i < 131072) { d7[(i&255)*512  + (i>>8)] = s7[i]; return; } i -= 131072;
    if (i < 524288) { d8[(i&511)*1024 + (i>>9)] = s8[i]; return; }
}

// ---------------------------------------------------------------------------
// Fused FPS (R10 variant) + weight-transpose blocks. (unchanged from R12)
// ---------------------------------------------------------------------------
template<int N, int NP1, int NP2, int BLOCK>
__global__ __launch_bounds__(BLOCK)
void fps_fused(const float* __restrict__ xyz,
               float* __restrict__ out1, float* __restrict__ out2,
               const float* __restrict__ ts0, float* __restrict__ td0,
               const float* __restrict__ ts1, float* __restrict__ td1,
               const float* __restrict__ ts2, float* __restrict__ td2,
               const float* __restrict__ ts3, float* __restrict__ td3,
               const float* __restrict__ ts4, float* __restrict__ td4,
               const float* __restrict__ ts5, float* __restrict__ td5,
               const float* __restrict__ ts6, float* __restrict__ td6,
               const float* __restrict__ ts7, float* __restrict__ td7,
               const float* __restrict__ ts8, float* __restrict__ td8)
{
#pragma clang fp contract(off)
    if ((int)blockIdx.x >= BATCH) {
        transpose_body(blockIdx.x - BATCH, threadIdx.x,
                       ts0, td0, ts1, td1, ts2, td2, ts3, td3, ts4, td4,
                       ts5, td5, ts6, td6, ts7, td7, ts8, td8);
        return;
    }
    constexpr int P  = N / BLOCK;
    constexpr int P2 = NP1 / BLOCK;
    constexpr int NW = BLOCK / 64;
    __shared__ float sx[N], sy[N], sz[N];
    __shared__ float s2x[NP1], s2y[NP1], s2z[NP1];
    __shared__ float o2x[NP2], o2y[NP2], o2z[NP2];
    __shared__ unsigned long long wslot[2][NW];
    const int b = blockIdx.x, t = threadIdx.x;
    const int lane = t & 63, wv = t >> 6;
    const float* xb = xyz + (size_t)b * N * 3;
    float px[P], py[P], pz[P], dist[P];
#pragma unroll
    for (int j = 0; j < P; ++j) {
        const int i = t + j * BLOCK;
        const float x = xb[i*3+0], y = xb[i*3+1], z = xb[i*3+2];
        sx[i] = x; sy[i] = y; sz[i] = z;
        px[j] = x; py[j] = y; pz[j] = z;
        dist[j] = 1e10f;
    }
    __syncthreads();
    float fx = sx[0], fy = sy[0], fz = sz[0];
    if (t == 0) { s2x[0] = fx; s2y[0] = fy; s2z[0] = fz; }
    for (int s = 1; s < NP1; ++s) {
        float bestv = -1.f; int besti = 0;
#pragma unroll
        for (int j = 0; j < P; ++j) {
            const float dx = px[j]-fx, dy = py[j]-fy, dz = pz[j]-fz;
            const float d = (dx*dx + dy*dy) + dz*dz;
            const float nd = fminf(dist[j], d);
            dist[j] = nd;
            if (nd > bestv) { bestv = nd; besti = t + j * BLOCK; }
        }
        const float wm = wave_max_bcast(bestv);
        const unsigned cand = (bestv == wm) ? (unsigned)besti : 0xffffffffu;
        const unsigned wi = wave_min_bcast(cand);
        const int par = s & 1;
        if (lane == 0)
            wslot[par][wv] = ((unsigned long long)__float_as_uint(wm) << 32)
                           | (unsigned)(~wi);
        __syncthreads();
        unsigned long long pa = wslot[par][0];
#pragma unroll
        for (int w = 1; w < NW; ++w) {
            const unsigned long long pb = wslot[par][w];
            pa = (pb > pa) ? pb : pa;
        }
        const int far = (int)(~(unsigned)pa);
        fx = sx[far]; fy = sy[far]; fz = sz[far];
        if (t == 0) { s2x[s] = fx; s2y[s] = fy; s2z[s] = fz; }
    }
    __syncthreads();
    // -------- stage 2 --------
    float mx[P2], my[P2], mz[P2], d2[P2];
#pragma unroll
    for (int j = 0; j < P2; ++j) {
        const int i = t + j * BLOCK;
        mx[j] = s2x[i]; my[j] = s2y[i]; mz[j] = s2z[i];
        d2[j] = 1e10f;
    }
    fx = s2x[0]; fy = s2y[0]; fz = s2z[0];
    if (t == 0) { o2x[0] = fx; o2y[0] = fy; o2z[0] = fz; }
    for (int s = 1; s < NP2; ++s) {
        float bestv = -1.f; int besti = 0;
#pragma unroll
        for (int j = 0; j < P2; ++j) {
            const float dx = mx[j]-fx, dy = my[j]-fy, dz = mz[j]-fz;
            const float d = (dx*dx + dy*dy) + dz*dz;
            const float nd = fminf(d2[j], d);
            d2[j] = nd;
            if (nd > bestv) { bestv = nd; besti = t + j * BLOCK; }
        }
        const float wm = wave_max_bcast(bestv);
        const unsigned cand = (bestv == wm) ? (unsigned)besti : 0xffffffffu;
        const unsigned wi = wave_min_bcast(cand);
        const int par = s & 1;
        if (lane == 0)
            wslot[par][wv] = ((unsigned long long)__float_as_uint(wm) << 32)
                           | (unsigned)(~wi);
        __syncthreads();
        unsigned long long pa = wslot[par][0];
#pragma unroll
        for (int w = 1; w < NW; ++w) {
            const unsigned long long pb = wslot[par][w];
            pa = (pb > pa) ? pb : pa;
        }
        const int far2 = (int)(~(unsigned)pa);
        fx = s2x[far2]; fy = s2y[far2]; fz = s2z[far2];
        if (t == 0) { o2x[s] = fx; o2y[s] = fy; o2z[s] = fz; }
    }
    __syncthreads();
    for (int i = t; i < NP1; i += BLOCK) {
        out1[((size_t)b*NP1 + i)*3 + 0] = s2x[i];
        out1[((size_t)b*NP1 + i)*3 + 1] = s2y[i];
        out1[((size_t)b*NP1 + i)*3 + 2] = s2z[i];
    }
    for (int i = t; i < NP2; i += BLOCK) {
        out2[((size_t)b*NP2 + i)*3 + 0] = o2x[i];
        out2[((size_t)b*NP2 + i)*3 + 1] = o2y[i];
        out2[((size_t)b*NP2 + i)*3 + 2] = o2z[i];
    }
}

// ---------------------------------------------------------------------------
// Ball query body + combined kernel (both levels in one launch)
// ---------------------------------------------------------------------------
template<int N, int S, int K>
__device__ __forceinline__ void ballq_body(const float* __restrict__ xyz,
                                           const float* __restrict__ nxyz,
                                           int* __restrict__ idx, const float r2,
                                           const int bid, const int tid)
{
#pragma clang fp contract(off)
    const int gw = (bid * 256 + tid) >> 6;
    const int lane = tid & 63;
    const int b = gw / S, s = gw % S;
    const float* xb = xyz + (size_t)b * N * 3;
    const float qx = nxyz[((size_t)b*S + s)*3 + 0];
    const float qy = nxyz[((size_t)b*S + s)*3 + 1];
    const float qz = nxyz[((size_t)b*S + s)*3 + 2];
    int* op = idx + ((size_t)b*S + s) * K;
    int base = 0, first = -1;
    for (int c = 0; c < N; c += 64) {
        const int i = c + lane;
        const float dx = xb[i*3+0]-qx, dy = xb[i*3+1]-qy, dz = xb[i*3+2]-qz;
        const float d = (dx*dx + dy*dy) + dz*dz;
        const bool hit = !(d > r2);
        const unsigned long long m = __ballot(hit);
        if (first < 0 && m) first = c + __builtin_ctzll(m);
        const int pos = base + __popcll(m & ((1ull << lane) - 1ull));
        if (hit && pos < K) op[pos] = i;
        base += __popcll(m);
        if (base >= K) break;
    }
    if (base < K && lane >= base && lane < K) op[lane] = first;
}

__global__ __launch_bounds__(256)
void ballq_both(const float* __restrict__ pts1, const float* __restrict__ q1,
                int* __restrict__ idx1, const float r2a,
                const float* __restrict__ pts2, const float* __restrict__ q2,
                int* __restrict__ idx2, const float r2b)
{
    const int nb1 = (BATCH * 512) / 4;
    if ((int)blockIdx.x < nb1)
        ballq_body<4096, 512, 32>(pts1, q1, idx1, r2a, blockIdx.x, threadIdx.x);
    else
        ballq_body<512, 128, 64>(pts2, q2, idx2, r2b, blockIdx.x - nb1, threadIdx.x);
}

// 8 packed FMAs against 16 contiguous transposed weights (bit-identical).
__device__ __forceinline__ void fma16pk(f32x2 (&acc)[8], const float f,
                                        const float* __restrict__ wrow)
{
    const float4 w0 = ((const float4*)wrow)[0];
    const float4 w1 = ((const float4*)wrow)[1];
    const float4 w2 = ((const float4*)wrow)[2];
    const float4 w3 = ((const float4*)wrow)[3];
    const f32x2 ff = mk2(f, f);
    acc[0] += ff * mk2(w0.x, w0.y);
    acc[1] += ff * mk2(w0.z, w0.w);
    acc[2] += ff * mk2(w1.x, w1.y);
    acc[3] += ff * mk2(w1.z, w1.w);
    acc[4] += ff * mk2(w2.x, w2.y);
    acc[5] += ff * mk2(w2.z, w2.w);
    acc[6] += ff * mk2(w3.x, w3.y);
    acc[7] += ff * mk2(w3.z, w3.w);
}

__device__ __forceinline__ float pool_half(float v)
{
    v = fmaxf(v, __shfl_xor(v, 1));
    v = fmaxf(v, __shfl_xor(v, 2));
    v = fmaxf(v, __shfl_xor(v, 4));
    v = fmaxf(v, __shfl_xor(v, 8));
    v = fmaxf(v, __shfl_xor(v, 16));
    return v;
}
__device__ __forceinline__ float pool_full(float v)
{
    v = pool_half(v);
    return fmaxf(v, __shfl_xor(v, 32));
}

// ---------------------------------------------------------------------------
// SA1 register-pure: NO LDS, NO barriers. Each lane owns one row end-to-end:
// h1[64] -> h2[64] in registers (1x1 conv is per-row; only maxpool crosses
// rows, done via shfl within the half-wave owning the K=32 group).
// Accumulation order per oc unchanged (ci ascending, bias first) -> bit-exact.
// Block = 256 thr = 4 independent waves, each covering 64 rows (2 groups).
// ---------------------------------------------------------------------------
__global__ __launch_bounds__(256)
void sa1_reg(const float* __restrict__ xyz, const float* __restrict__ nxyz,
             const int* __restrict__ idx,
             const float* __restrict__ Wt0, const float* __restrict__ B0,
             const float* __restrict__ Wt1, const float* __restrict__ B1,
             const float* __restrict__ Wt2, const float* __restrict__ B2,
             float* __restrict__ out)
{
    const int tid = threadIdx.x, lane = tid & 63;
    const int wave = __builtin_amdgcn_readfirstlane(tid >> 6);
    const int myrow = blockIdx.x * 256 + wave * 64 + lane;
    const int g = myrow >> 5, b = g >> 9;
    const int i = idx[myrow];
    const float* p = xyz + ((size_t)b*4096 + i) * 3;
    const float f0 = p[0] - nxyz[(size_t)g*3 + 0];
    const float f1 = p[1] - nxyz[(size_t)g*3 + 1];
    const float f2 = p[2] - nxyz[(size_t)g*3 + 2];
    // L1: 3 -> 64, all in registers
    float h1[64];
#pragma unroll
    for (int oc = 0; oc < 64; ++oc)
        h1[oc] = fmaxf(B0[oc] + f0*Wt0[0*64+oc] + f1*Wt0[1*64+oc] + f2*Wt0[2*64+oc], 0.f);
    // L2: 64 -> 64, 16 ocs per chunk, h1 static-indexed (full unroll)
    float h2[64];
#pragma unroll
    for (int ch = 0; ch < 4; ++ch) {
        const int oc0 = ch * 16;
        f32x2 acc[8];
#pragma unroll
        for (int k = 0; k < 8; ++k) acc[k] = mk2(B1[oc0+2*k], B1[oc0+2*k+1]);
#pragma unroll
        for (int ci = 0; ci < 64; ++ci)
            fma16pk(acc, h1[ci], Wt1 + ci*64 + oc0);
#pragma unroll
        for (int k = 0; k < 8; ++k) {
            h2[oc0+2*k]   = fmaxf(acc[k].x, 0.f);
            h2[oc0+2*k+1] = fmaxf(acc[k].y, 0.f);
        }
    }
    // L3: 64 -> 128 in 8 chunks of 16 + maxpool over K=32 (half-wave)
    const size_t orow = (size_t)g * 128;
#pragma unroll
    for (int ch = 0; ch < 8; ++ch) {
        const int oc0 = ch * 16;
        f32x2 acc[8];
#pragma unroll
        for (int k = 0; k < 8; ++k) acc[k] = mk2(B2[oc0+2*k], B2[oc0+2*k+1]);
#pragma unroll
        for (int ci = 0; ci < 64; ++ci)
            fma16pk(acc, h2[ci], Wt2 + ci*128 + oc0);
#pragma unroll
        for (int k = 0; k < 8; ++k) {
            const float v0 = pool_half(fmaxf(acc[k].x, 0.f));
            const float v1 = pool_half(fmaxf(acc[k].y, 0.f));
            if ((lane & 31) == 0) {
                out[orow + ((lane >> 5) ? 0 : 0) + oc0 + 2*k]     = v0;   // lane0 -> group g
                out[orow + oc0 + 2*k + 1] = v1;
            }
        }
    }
}

// ---------------------------------------------------------------------------
// SA2 fused, in-place 32 KB buffer, packed-FMA accumulators. (unchanged)
// ---------------------------------------------------------------------------
__global__ __launch_bounds__(256)
void sa2_fused(const float* __restrict__ l1xyz, const float* __restrict__ l1pts,
               const float* __restrict__ nxyz, const int* __restrict__ idx,
               const float* __restrict__ Wt0, const float* __restrict__ B0,
               const float* __restrict__ Wt1, const float* __restrict__ B1,
               const float* __restrict__ Wt2, const float* __restrict__ B2,
               float* __restrict__ out)
{
    __shared__ float buf[128][64];
    const int tid = threadIdx.x, lane = tid & 63;
    const int wave = __builtin_amdgcn_readfirstlane(tid >> 6);
    const int gblk = blockIdx.x;
    const int b = gblk >> 7;
    const int row0 = gblk * 64;
    const int myi = idx[row0 + lane];
    const float* pc = l1xyz + ((size_t)b*512 + myi) * 3;
    const float f0 = pc[0] - nxyz[(size_t)gblk*3 + 0];
    const float f1 = pc[1] - nxyz[(size_t)gblk*3 + 1];
    const float f2 = pc[2] - nxyz[(size_t)gblk*3 + 2];
    for (int r = wave; r < 64; r += 4) {
        const int i2 = idx[row0 + r];
        const float* src = l1pts + ((size_t)b*512 + i2) * 128;
        buf[lane][r ^ lane]    = src[lane];
        buf[lane+64][r ^ lane] = src[lane + 64];
    }
    __syncthreads();
    const int oc0 = wave * 16;
    f32x2 aL[8], aH[8];
#pragma unroll
    for (int k = 0; k < 8; ++k) {
        const int j0 = oc0 + 2*k, j1 = oc0 + 2*k + 1;
        aL[k] = mk2(B0[j0]    + f0*Wt0[j0]     + f1*Wt0[128+j0]    + f2*Wt0[256+j0],
                    B0[j1]    + f0*Wt0[j1]     + f1*Wt0[128+j1]    + f2*Wt0[256+j1]);
        aH[k] = mk2(B0[64+j0] + f0*Wt0[64+j0]  + f1*Wt0[192+j0]    + f2*Wt0[320+j0],
                    B0[64+j1] + f0*Wt0[64+j1]  + f1*Wt0[192+j1]    + f2*Wt0[320+j1]);
    }
#pragma unroll 2
    for (int ci = 0; ci < 128; ++ci) {
        const float f = buf[ci][lane ^ (ci & 63)];
        const float* wp = Wt0 + (size_t)(ci+3)*128;
        fma16pk(aL, f, wp + oc0);
        fma16pk(aH, f, wp + 64 + oc0);
    }
    __syncthreads();
#pragma unroll
    for (int k = 0; k < 8; ++k) {
        buf[oc0+2*k][lane]      = fmaxf(aL[k].x, 0.f);
        buf[oc0+2*k+1][lane]    = fmaxf(aL[k].y, 0.f);
        buf[64+oc0+2*k][lane]   = fmaxf(aH[k].x, 0.f);
        buf[64+oc0+2*k+1][lane] = fmaxf(aH[k].y, 0.f);
    }
    __syncthreads();
#pragma unroll
    for (int k = 0; k < 8; ++k) {
        aL[k] = mk2(B1[oc0+2*k], B1[oc0+2*k+1]);
        aH[k] = mk2(B1[64+oc0+2*k], B1[64+oc0+2*k+1]);
    }
#pragma unroll 2
    for (int ci = 0; ci < 128; ++ci) {
        const float f = buf[ci][lane];
        const float* wp = Wt1 + (size_t)ci*128;
        fma16pk(aL, f, wp + oc0);
        fma16pk(aH, f, wp + 64 + oc0);
    }
    __syncthreads();
#pragma unroll
    for (int k = 0; k < 8; ++k) {
        buf[oc0+2*k][lane]      = fmaxf(aL[k].x, 0.f);
        buf[oc0+2*k+1][lane]    = fmaxf(aL[k].y, 0.f);
        buf[64+oc0+2*k][lane]   = fmaxf(aH[k].x, 0.f);
        buf[64+oc0+2*k+1][lane] = fmaxf(aH[k].y, 0.f);
    }
    __syncthreads();
    float* orow = out + (size_t)gblk * 256;
    for (int half = 0; half < 2; ++half) {
        const int oc = half*128 + oc0;
#pragma unroll
        for (int k = 0; k < 8; ++k) {
            aL[k] = mk2(B2[oc+2*k], B2[oc+2*k+1]);
            aH[k] = mk2(B2[64+oc+2*k], B2[64+oc+2*k+1]);
        }
#pragma unroll 2
        for (int ci = 0; ci < 128; ++ci) {
            const float f = buf[ci][lane];
            const float* wp = Wt2 + (size_t)ci*256;
            fma16pk(aL, f, wp + oc);
            fma16pk(aH, f, wp + 64 + oc);
        }
#pragma unroll
        for (int k = 0; k < 8; ++k) {
            const float v0 = pool_full(fmaxf(aL[k].x, 0.f));
            const float v1 = pool_full(fmaxf(aL[k].y, 0.f));
            const float w0 = pool_full(fmaxf(aH[k].x, 0.f));
            const float w1 = pool_full(fmaxf(aH[k].y, 0.f));
            if (lane == 0) {
                orow[oc + 2*k]        = v0;
                orow[oc + 2*k + 1]    = v1;
                orow[64 + oc + 2*k]   = w0;
                orow[64 + oc + 2*k+1] = w1;
            }
        }
    }
}

// ---------------------------------------------------------------------------
// SA3 GEMM layers, packed-FMA accumulators. (unchanged)
// ---------------------------------------------------------------------------
template<int CIN, int COUT, bool CONCAT3, bool POOL>
__global__ __launch_bounds__(256)
void mlp_gemm_kernel(const float* __restrict__ inA, const float* __restrict__ inB,
                     const float* __restrict__ Wt, const float* __restrict__ Bb,
                     float* __restrict__ out)
{
    __shared__ float featS[128][64];
    const int tid = threadIdx.x, lane = tid & 63;
    const int wave = __builtin_amdgcn_readfirstlane(tid >> 6);
    const int row0 = blockIdx.x * 64;
    const int oc0 = blockIdx.y * 64 + wave * 16;
    f32x2 acc[8];
#pragma unroll
    for (int k = 0; k < 8; ++k) acc[k] = mk2(Bb[oc0+2*k], Bb[oc0+2*k+1]);
    for (int c0 = 0; c0 < CIN; c0 += 128) {
        const int csz = (CIN - c0 < 128) ? (CIN - c0) : 128;
        __syncthreads();
        for (int r = wave; r < 64; r += 4) {
            const int row = row0 + r;
            for (int cl = lane; cl < csz; cl += 64) {
                const int cig = c0 + cl;
                float v;
                if (CONCAT3)
                    v = (cig < 3) ? inA[(size_t)row*3 + cig]
                                  : inB[(size_t)row*(CIN-3) + (cig - 3)];
                else
                    v = inA[(size_t)row*CIN + cig];
                featS[cl][r ^ (cl & 63)] = v;
            }
        }
        __syncthreads();
        if (csz == 128) {
#pragma unroll 4
            for (int ci = 0; ci < 128; ++ci)
                fma16pk(acc, featS[ci][lane ^ (ci & 63)], Wt + (size_t)(c0+ci)*COUT + oc0);
        } else {
            for (int ci = 0; ci < csz; ++ci)
                fma16pk(acc, featS[ci][lane ^ (ci & 63)], Wt + (size_t)(c0+ci)*COUT + oc0);
        }
    }
    if (POOL) {
#pragma unroll
        for (int k = 0; k < 8; ++k) {
            const float v0 = pool_full(fmaxf(acc[k].x, 0.f));
            const float v1 = pool_full(fmaxf(acc[k].y, 0.f));
            if (lane == 0) {
                out[(size_t)blockIdx.x * COUT + oc0 + 2*k]     = v0;
                out[(size_t)blockIdx.x * COUT + oc0 + 2*k + 1] = v1;
            }
        }
    } else {
        float4 o0, o1, o2, o3;
        o0.x=fmaxf(acc[0].x,0.f); o0.y=fmaxf(acc[0].y,0.f); o0.z=fmaxf(acc[1].x,0.f); o0.w=fmaxf(acc[1].y,0.f);
        o1.x=fmaxf(acc[2].x,0.f); o1.y=fmaxf(acc[2].y,0.f); o1.z=fmaxf(acc[3].x,0.f); o1.w=fmaxf(acc[3].y,0.f);
        o2.x=fmaxf(acc[4].x,0.f); o2.y=fmaxf(acc[4].y,0.f); o2.z=fmaxf(acc[5].x,0.f); o2.w=fmaxf(acc[5].y,0.f);
        o3.x=fmaxf(acc[6].x,0.f); o3.y=fmaxf(acc[6].y,0.f); o3.z=fmaxf(acc[7].x,0.f); o3.w=fmaxf(acc[7].y,0.f);
        float4* op = (float4*)(out + (size_t)(row0 + lane)*COUT + oc0);
        op[0]=o0; op[1]=o1; op[2]=o2; op[3]=o3;
    }
}

// y[b][o] = fb[o] + max(pmax[2b], pmax[2b+1]) . fw[o]; one wave per output
__global__ __launch_bounds__(256)
void fc_kernel(const float* __restrict__ pmax, const float* __restrict__ fw,
               const float* __restrict__ fb, float* __restrict__ y)
{
    const int gw = (blockIdx.x * 256 + threadIdx.x) >> 6;
    const int lane = threadIdx.x & 63;
    const int b = gw >> 10, o = gw & 1023;
    const float4* g0 = (const float4*)(pmax + (size_t)(2*b) * 1024);
    const float4* g1 = (const float4*)(pmax + (size_t)(2*b+1) * 1024);
    const float4* wv = (const float4*)(fw + (size_t)o * 1024);
    float acc = 0.f;
#pragma unroll
    for (int r = 0; r < 4; ++r) {
        const float4 a = g0[lane + r*64];
        const float4 c = g1[lane + r*64];
        const float4 w = wv[lane + r*64];
        acc += fmaxf(a.x,c.x)*w.x + fmaxf(a.y,c.y)*w.y
             + fmaxf(a.z,c.z)*w.z + fmaxf(a.w,c.w)*w.w;
    }
#pragma unroll
    for (int m = 32; m >= 1; m >>= 1) acc += __shfl_xor(acc, m);
    if (lane == 0) y[gw] = acc + fb[o];
}

extern "C" void kernel_launch(void* const* d_in, const int* in_sizes, int n_in,
                              void* d_out, int out_size, void* d_ws, size_t ws_size,
                              hipStream_t stream)
{
    (void)in_sizes; (void)n_in; (void)out_size; (void)ws_size;
    const float* x   = (const float*)d_in[0];
    const float* s1w0 = (const float*)d_in[1];  const float* s1b0 = (const float*)d_in[2];
    const float* s1w1 = (const float*)d_in[3];  const float* s1b1 = (const float*)d_in[4];
    const float* s1w2 = (const float*)d_in[5];  const float* s1b2 = (const float*)d_in[6];
    const float* s2w0 = (const float*)d_in[7];  const float* s2b0 = (const float*)d_in[8];
    const float* s2w1 = (const float*)d_in[9];  const float* s2b1 = (const float*)d_in[10];
    const float* s2w2 = (const float*)d_in[11]; const float* s2b2 = (const float*)d_in[12];
    const float* s3w0 = (const float*)d_in[13]; const float* s3b0 = (const float*)d_in[14];
    const float* s3w1 = (const float*)d_in[15]; const float* s3b1 = (const float*)d_in[16];
    const float* s3w2 = (const float*)d_in[17]; const float* s3b2 = (const float*)d_in[18];
    const float* fw  = (const float*)d_in[19]; const float* fb  = (const float*)d_in[20];
    float* y = (float*)d_out;

    char* ws = (char*)d_ws;
    float* l1_xyz = (float*)(ws + 0);          // 16*512*3
    int*   idx1   = (int*)  (ws + 98304);      // 16*512*32
    float* l1_pts = (float*)(ws + 1146880);    // 16*512*128
    float* l2_xyz = (float*)(ws + 5341184);    // 16*128*3
    int*   idx2   = (int*)  (ws + 5365760);    // 16*128*64
    float* l2_pts = (float*)(ws + 5890048);    // 16*128*256
    float* h1     = (float*)(ws + 7987200);    // 2048*256
    float* h2     = (float*)(ws + 10084352);   // 2048*512
    float* pmax   = (float*)(ws + 14278656);   // 32*1024 partial maxes
    float* wt1_0  = (float*)(ws + 14409728);   // [3][64]
    float* wt1_1  = (float*)(ws + 14410496);   // [64][64]
    float* wt1_2  = (float*)(ws + 14426880);   // [64][128]
    float* wt2_0  = (float*)(ws + 14459648);   // [131][128]
    float* wt2_1  = (float*)(ws + 14526720);   // [128][128]
    float* wt2_2  = (float*)(ws + 14592256);   // [128][256]
    float* wt3_0  = (float*)(ws + 14723328);   // [259][256]
    float* wt3_1  = (float*)(ws + 14988544);   // [256][512]
    float* wt3_2  = (float*)(ws + 15512832);   // [512][1024]

    const float r2_1 = (float)(0.2 * 0.2);
    const float r2_2 = (float)(0.4 * 0.4);

    fps_fused<4096, 512, 128, 256><<<BATCH + 3126, 256, 0, stream>>>(
        x, l1_xyz, l2_xyz,
        s1w0, wt1_0, s1w1, wt1_1, s1w2, wt1_2,
        s2w0, wt2_0, s2w1, wt2_1, s2w2, wt2_2,
        s3w0, wt3_0, s3w1, wt3_1, s3w2, wt3_2);
    ballq_both<<<(BATCH*512)/4 + (BATCH*128)/4, 256, 0, stream>>>(
        x, l1_xyz, idx1, r2_1, l1_xyz, l2_xyz, idx2, r2_2);
    sa1_reg<<<(BATCH*512*32)/256, 256, 0, stream>>>(x, l1_xyz, idx1,
        wt1_0, s1b0, wt1_1, s1b1, wt1_2, s1b2, l1_pts);
    sa2_fused<<<BATCH*128, 256, 0, stream>>>(l1_xyz, l1_pts, l2_xyz, idx2,
        wt2_0, s2b0, wt2_1, s2b1, wt2_2, s2b2, l2_pts);
    mlp_gemm_kernel<259, 256,  true,  false><<<dim3(32, 4),  256, 0, stream>>>(l2_xyz, l2_pts, wt3_0, s3b0, h1);
    mlp_gemm_kernel<256, 512,  false, false><<<dim3(32, 8),  256, 0, stream>>>(h1, nullptr, wt3_1, s3b1, h2);
    mlp_gemm_kernel<512, 1024, false, true ><<<dim3(32, 16), 256, 0, stream>>>(h2, nullptr, wt3_2, s3b2, pmax);
    fc_kernel<<<(BATCH*1024)/4, 256, 0, stream>>>(pmax, fw, fb, y);
}

// Round 14
// 893.737 us; speedup vs baseline: 1.6300x; 1.6300x over previous
//
#include <hip/hip_runtime.h>

#ifndef BATCH
#define BATCH 16
#endif

typedef float f32x2 __attribute__((ext_vector_type(2)));
__device__ __forceinline__ f32x2 mk2(float a, float b) { f32x2 r; r.x = a; r.y = b; return r; }

// ---- DPP wave64 reduction helpers (row_shr scan + row_bcast merge) --------
template<int CTRL>
__device__ __forceinline__ float dppmaxf(float v)
{
    const int d = __builtin_amdgcn_update_dpp(__float_as_int(v), __float_as_int(v),
                                              CTRL, 0xf, 0xf, false);
    return fmaxf(v, __int_as_float(d));
}
template<int CTRL>
__device__ __forceinline__ unsigned dppminu(unsigned v)
{
    const unsigned d = (unsigned)__builtin_amdgcn_update_dpp((int)v, (int)v,
                                                             CTRL, 0xf, 0xf, false);
    return (d < v) ? d : v;
}
__device__ __forceinline__ float wave_max_bcast(float v)
{
    v = dppmaxf<0x111>(v);
    v = dppmaxf<0x112>(v);
    v = dppmaxf<0x114>(v);
    v = dppmaxf<0x118>(v);
    v = dppmaxf<0x142>(v);
    v = dppmaxf<0x143>(v);
    return __int_as_float(__builtin_amdgcn_readlane(__float_as_int(v), 63));
}
__device__ __forceinline__ unsigned wave_min_bcast(unsigned v)
{
    v = dppminu<0x111>(v);
    v = dppminu<0x112>(v);
    v = dppminu<0x114>(v);
    v = dppminu<0x118>(v);
    v = dppminu<0x142>(v);
    v = dppminu<0x143>(v);
    return (unsigned)__builtin_amdgcn_readlane((int)v, 63);
}

// ---- transpose body: W[O][C] -> Wt[C][O], flat index space ----------------
__device__ __forceinline__ void transpose_body(int blk, int tid,
    const float* __restrict__ s0, float* __restrict__ d0,
    const float* __restrict__ s1, float* __restrict__ d1,
    const float* __restrict__ s2, float* __restrict__ d2,
    const float* __restrict__ s3, float* __restrict__ d3,
    const float* __restrict__ s4, float* __restrict__ d4,
    const float* __restrict__ s5, float* __restrict__ d5,
    const float* __restrict__ s6, float* __restrict__ d6,
    const float* __restrict__ s7, float* __restrict__ d7,
    const float* __restrict__ s8, float* __restrict__ d8)
{
    int i = blk * 256 + tid;
    if (i < 192)    { d0[(i%3)  *64   + i/3  ] = s0[i]; return; }  i -= 192;
    if (i < 4096)   { d1[(i&63) *64   + (i>>6)] = s1[i]; return; } i -= 4096;
    if (i < 8192)   { d2[(i&63) *128  + (i>>6)] = s2[i]; return; } i -= 8192;
    if (i < 16768)  { d3[(i%131)*128  + i/131] = s3[i]; return; }  i -= 16768;
    if (i < 16384)  { d4[(i&127)*128  + (i>>7)] = s4[i]; return; } i -= 16384;
    if (i < 32768)  { d5[(i&127)*256  + (i>>7)] = s5[i]; return; } i -= 32768;
    if (i < 66304)  { d6[(i%259)*256  + i/259] = s6[i]; return; }  i -= 66304;
    if (i < 131072) { d7[(i&255)*512  + (i>>8)] = s7[i]; return; } i -= 131072;
    if (i < 524288) { d8[(i&511)*1024 + (i>>9)] = s8[i]; return; }
}

// ---------------------------------------------------------------------------
// Fused FPS (R10 variant) + weight-transpose blocks. (unchanged from R12)
// ---------------------------------------------------------------------------
template<int N, int NP1, int NP2, int BLOCK>
__global__ __launch_bounds__(BLOCK)
void fps_fused(const float* __restrict__ xyz,
               float* __restrict__ out1, float* __restrict__ out2,
               const float* __restrict__ ts0, float* __restrict__ td0,
               const float* __restrict__ ts1, float* __restrict__ td1,
               const float* __restrict__ ts2, float* __restrict__ td2,
               const float* __restrict__ ts3, float* __restrict__ td3,
               const float* __restrict__ ts4, float* __restrict__ td4,
               const float* __restrict__ ts5, float* __restrict__ td5,
               const float* __restrict__ ts6, float* __restrict__ td6,
               const float* __restrict__ ts7, float* __restrict__ td7,
               const float* __restrict__ ts8, float* __restrict__ td8)
{
#pragma clang fp contract(off)
    if ((int)blockIdx.x >= BATCH) {
        transpose_body(blockIdx.x - BATCH, threadIdx.x,
                       ts0, td0, ts1, td1, ts2, td2, ts3, td3, ts4, td4,
                       ts5, td5, ts6, td6, ts7, td7, ts8, td8);
        return;
    }
    constexpr int P  = N / BLOCK;
    constexpr int P2 = NP1 / BLOCK;
    constexpr int NW = BLOCK / 64;
    __shared__ float sx[N], sy[N], sz[N];
    __shared__ float s2x[NP1], s2y[NP1], s2z[NP1];
    __shared__ float o2x[NP2], o2y[NP2], o2z[NP2];
    __shared__ unsigned long long wslot[2][NW];
    const int b = blockIdx.x, t = threadIdx.x;
    const int lane = t & 63, wv = t >> 6;
    const float* xb = xyz + (size_t)b * N * 3;
    float px[P], py[P], pz[P], dist[P];
#pragma unroll
    for (int j = 0; j < P; ++j) {
        const int i = t + j * BLOCK;
        const float x = xb[i*3+0], y = xb[i*3+1], z = xb[i*3+2];
        sx[i] = x; sy[i] = y; sz[i] = z;
        px[j] = x; py[j] = y; pz[j] = z;
        dist[j] = 1e10f;
    }
    __syncthreads();
    float fx = sx[0], fy = sy[0], fz = sz[0];
    if (t == 0) { s2x[0] = fx; s2y[0] = fy; s2z[0] = fz; }
    for (int s = 1; s < NP1; ++s) {
        float bestv = -1.f; int besti = 0;
#pragma unroll
        for (int j = 0; j < P; ++j) {
            const float dx = px[j]-fx, dy = py[j]-fy, dz = pz[j]-fz;
            const float d = (dx*dx + dy*dy) + dz*dz;
            const float nd = fminf(dist[j], d);
            dist[j] = nd;
            if (nd > bestv) { bestv = nd; besti = t + j * BLOCK; }
        }
        const float wm = wave_max_bcast(bestv);
        const unsigned cand = (bestv == wm) ? (unsigned)besti : 0xffffffffu;
        const unsigned wi = wave_min_bcast(cand);
        const int par = s & 1;
        if (lane == 0)
            wslot[par][wv] = ((unsigned long long)__float_as_uint(wm) << 32)
                           | (unsigned)(~wi);
        __syncthreads();
        unsigned long long pa = wslot[par][0];
#pragma unroll
        for (int w = 1; w < NW; ++w) {
            const unsigned long long pb = wslot[par][w];
            pa = (pb > pa) ? pb : pa;
        }
        const int far = (int)(~(unsigned)pa);
        fx = sx[far]; fy = sy[far]; fz = sz[far];
        if (t == 0) { s2x[s] = fx; s2y[s] = fy; s2z[s] = fz; }
    }
    __syncthreads();
    // -------- stage 2 --------
    float mx[P2], my[P2], mz[P2], d2[P2];
#pragma unroll
    for (int j = 0; j < P2; ++j) {
        const int i = t + j * BLOCK;
        mx[j] = s2x[i]; my[j] = s2y[i]; mz[j] = s2z[i];
        d2[j] = 1e10f;
    }
    fx = s2x[0]; fy = s2y[0]; fz = s2z[0];
    if (t == 0) { o2x[0] = fx; o2y[0] = fy; o2z[0] = fz; }
    for (int s = 1; s < NP2; ++s) {
        float bestv = -1.f; int besti = 0;
#pragma unroll
        for (int j = 0; j < P2; ++j) {
            const float dx = mx[j]-fx, dy = my[j]-fy, dz = mz[j]-fz;
            const float d = (dx*dx + dy*dy) + dz*dz;
            const float nd = fminf(d2[j], d);
            d2[j] = nd;
            if (nd > bestv) { bestv = nd; besti = t + j * BLOCK; }
        }
        const float wm = wave_max_bcast(bestv);
        const unsigned cand = (bestv == wm) ? (unsigned)besti : 0xffffffffu;
        const unsigned wi = wave_min_bcast(cand);
        const int par = s & 1;
        if (lane == 0)
            wslot[par][wv] = ((unsigned long long)__float_as_uint(wm) << 32)
                           | (unsigned)(~wi);
        __syncthreads();
        unsigned long long pa = wslot[par][0];
#pragma unroll
        for (int w = 1; w < NW; ++w) {
            const unsigned long long pb = wslot[par][w];
            pa = (pb > pa) ? pb : pa;
        }
        const int far2 = (int)(~(unsigned)pa);
        fx = s2x[far2]; fy = s2y[far2]; fz = s2z[far2];
        if (t == 0) { o2x[s] = fx; o2y[s] = fy; o2z[s] = fz; }
    }
    __syncthreads();
    for (int i = t; i < NP1; i += BLOCK) {
        out1[((size_t)b*NP1 + i)*3 + 0] = s2x[i];
        out1[((size_t)b*NP1 + i)*3 + 1] = s2y[i];
        out1[((size_t)b*NP1 + i)*3 + 2] = s2z[i];
    }
    for (int i = t; i < NP2; i += BLOCK) {
        out2[((size_t)b*NP2 + i)*3 + 0] = o2x[i];
        out2[((size_t)b*NP2 + i)*3 + 1] = o2y[i];
        out2[((size_t)b*NP2 + i)*3 + 2] = o2z[i];
    }
}

// ---------------------------------------------------------------------------
// Ball query body + combined kernel (both levels in one launch)
// ---------------------------------------------------------------------------
template<int N, int S, int K>
__device__ __forceinline__ void ballq_body(const float* __restrict__ xyz,
                                           const float* __restrict__ nxyz,
                                           int* __restrict__ idx, const float r2,
                                           const int bid, const int tid)
{
#pragma clang fp contract(off)
    const int gw = (bid * 256 + tid) >> 6;
    const int lane = tid & 63;
    const int b = gw / S, s = gw % S;
    const float* xb = xyz + (size_t)b * N * 3;
    const float qx = nxyz[((size_t)b*S + s)*3 + 0];
    const float qy = nxyz[((size_t)b*S + s)*3 + 1];
    const float qz = nxyz[((size_t)b*S + s)*3 + 2];
    int* op = idx + ((size_t)b*S + s) * K;
    int base = 0, first = -1;
    for (int c = 0; c < N; c += 64) {
        const int i = c + lane;
        const float dx = xb[i*3+0]-qx, dy = xb[i*3+1]-qy, dz = xb[i*3+2]-qz;
        const float d = (dx*dx + dy*dy) + dz*dz;
        const bool hit = !(d > r2);
        const unsigned long long m = __ballot(hit);
        if (first < 0 && m) first = c + __builtin_ctzll(m);
        const int pos = base + __popcll(m & ((1ull << lane) - 1ull));
        if (hit && pos < K) op[pos] = i;
        base += __popcll(m);
        if (base >= K) break;
    }
    if (base < K && lane >= base && lane < K) op[lane] = first;
}

__global__ __launch_bounds__(256)
void ballq_both(const float* __restrict__ pts1, const float* __restrict__ q1,
                int* __restrict__ idx1, const float r2a,
                const float* __restrict__ pts2, const float* __restrict__ q2,
                int* __restrict__ idx2, const float r2b)
{
    const int nb1 = (BATCH * 512) / 4;
    if ((int)blockIdx.x < nb1)
        ballq_body<4096, 512, 32>(pts1, q1, idx1, r2a, blockIdx.x, threadIdx.x);
    else
        ballq_body<512, 128, 64>(pts2, q2, idx2, r2b, blockIdx.x - nb1, threadIdx.x);
}

// 8 packed FMAs against 16 contiguous transposed weights (bit-identical).
__device__ __forceinline__ void fma16pk(f32x2 (&acc)[8], const float f,
                                        const float* __restrict__ wrow)
{
    const float4 w0 = ((const float4*)wrow)[0];
    const float4 w1 = ((const float4*)wrow)[1];
    const float4 w2 = ((const float4*)wrow)[2];
    const float4 w3 = ((const float4*)wrow)[3];
    const f32x2 ff = mk2(f, f);
    acc[0] += ff * mk2(w0.x, w0.y);
    acc[1] += ff * mk2(w0.z, w0.w);
    acc[2] += ff * mk2(w1.x, w1.y);
    acc[3] += ff * mk2(w1.z, w1.w);
    acc[4] += ff * mk2(w2.x, w2.y);
    acc[5] += ff * mk2(w2.z, w2.w);
    acc[6] += ff * mk2(w3.x, w3.y);
    acc[7] += ff * mk2(w3.z, w3.w);
}

__device__ __forceinline__ float pool_half(float v)
{
    v = fmaxf(v, __shfl_xor(v, 1));
    v = fmaxf(v, __shfl_xor(v, 2));
    v = fmaxf(v, __shfl_xor(v, 4));
    v = fmaxf(v, __shfl_xor(v, 8));
    v = fmaxf(v, __shfl_xor(v, 16));
    return v;
}
__device__ __forceinline__ float pool_full(float v)
{
    v = pool_half(v);
    return fmaxf(v, __shfl_xor(v, 32));
}

// ---------------------------------------------------------------------------
// SA1 fused, in-place 16 KB LDS buffer (R12 version -- reverted from the
// scratch-spilling sa1_reg experiment).
// ---------------------------------------------------------------------------
__global__ __launch_bounds__(256)
void sa1_fused(const float* __restrict__ xyz, const float* __restrict__ nxyz,
               const int* __restrict__ idx,
               const float* __restrict__ Wt0, const float* __restrict__ B0,
               const float* __restrict__ Wt1, const float* __restrict__ B1,
               const float* __restrict__ Wt2, const float* __restrict__ B2,
               float* __restrict__ out)
{
    __shared__ float buf[64][64];
    const int tid = threadIdx.x, lane = tid & 63;
    const int wave = __builtin_amdgcn_readfirstlane(tid >> 6);
    const int row0 = blockIdx.x * 64;
    const int myrow = row0 + lane;
    const int g = myrow >> 5, b = g >> 9;
    const int i = idx[myrow];
    const float* p = xyz + ((size_t)b*4096 + i) * 3;
    const float f0 = p[0] - nxyz[(size_t)g*3 + 0];
    const float f1 = p[1] - nxyz[(size_t)g*3 + 1];
    const float f2 = p[2] - nxyz[(size_t)g*3 + 2];
    const int oc0 = wave * 16;
    f32x2 aL[8], aH[8];
#pragma unroll
    for (int j = 0; j < 16; ++j) {
        const float v = B0[oc0+j] + f0*Wt0[0*64+oc0+j] + f1*Wt0[1*64+oc0+j] + f2*Wt0[2*64+oc0+j];
        buf[oc0+j][lane] = fmaxf(v, 0.f);
    }
    __syncthreads();
#pragma unroll
    for (int k = 0; k < 8; ++k) aL[k] = mk2(B1[oc0+2*k], B1[oc0+2*k+1]);
#pragma unroll 4
    for (int ci = 0; ci < 64; ++ci)
        fma16pk(aL, buf[ci][lane], Wt1 + ci*64 + oc0);
    __syncthreads();
#pragma unroll
    for (int k = 0; k < 8; ++k) {
        buf[oc0+2*k][lane]   = fmaxf(aL[k].x, 0.f);
        buf[oc0+2*k+1][lane] = fmaxf(aL[k].y, 0.f);
    }
    __syncthreads();
#pragma unroll
    for (int k = 0; k < 8; ++k) {
        aL[k] = mk2(B2[oc0+2*k], B2[oc0+2*k+1]);
        aH[k] = mk2(B2[64+oc0+2*k], B2[64+oc0+2*k+1]);
    }
#pragma unroll 2
    for (int ci = 0; ci < 64; ++ci) {
        const float f = buf[ci][lane];
        fma16pk(aL, f, Wt2 + ci*128 + oc0);
        fma16pk(aH, f, Wt2 + ci*128 + 64 + oc0);
    }
#pragma unroll
    for (int k = 0; k < 8; ++k) {
        const float v0 = pool_half(fmaxf(aL[k].x, 0.f));
        const float v1 = pool_half(fmaxf(aL[k].y, 0.f));
        const float w0 = pool_half(fmaxf(aH[k].x, 0.f));
        const float w1 = pool_half(fmaxf(aH[k].y, 0.f));
        if ((lane & 31) == 0) {
            const size_t orow = (size_t)((row0 + lane) >> 5) * 128;
            out[orow + oc0 + 2*k]       = v0;
            out[orow + oc0 + 2*k + 1]   = v1;
            out[orow + 64 + oc0 + 2*k]     = w0;
            out[orow + 64 + oc0 + 2*k + 1] = w1;
        }
    }
}

// ---------------------------------------------------------------------------
// SA2 fused + SA3-layer-1 epilogue. In-place 32 KB buffer + 1 KB pool.
// Each block produces one pooled row (256 vals); instead of writing l2_pts,
// it computes h1row[256] = relu(W3_0 . [center_xyz | pooled]) directly
// (one oc per thread, ci ascending => same accumulation chain as the old
// mlp_gemm<259,256,CONCAT3> kernel). Saves that kernel + the l2_pts
// global round-trip.
// ---------------------------------------------------------------------------
__global__ __launch_bounds__(256)
void sa2_fused(const float* __restrict__ l1xyz, const float* __restrict__ l1pts,
               const float* __restrict__ nxyz, const int* __restrict__ idx,
               const float* __restrict__ Wt0, const float* __restrict__ B0,
               const float* __restrict__ Wt1, const float* __restrict__ B1,
               const float* __restrict__ Wt2, const float* __restrict__ B2,
               const float* __restrict__ Wt30, const float* __restrict__ B30,
               float* __restrict__ outH1)
{
    __shared__ float buf[128][64];
    __shared__ float pool[256];
    const int tid = threadIdx.x, lane = tid & 63;
    const int wave = __builtin_amdgcn_readfirstlane(tid >> 6);
    const int gblk = blockIdx.x;
    const int b = gblk >> 7;
    const int row0 = gblk * 64;
    const int myi = idx[row0 + lane];
    const float* pc = l1xyz + ((size_t)b*512 + myi) * 3;
    const float cx = nxyz[(size_t)gblk*3 + 0];
    const float cy = nxyz[(size_t)gblk*3 + 1];
    const float cz = nxyz[(size_t)gblk*3 + 2];
    const float f0 = pc[0] - cx;
    const float f1 = pc[1] - cy;
    const float f2 = pc[2] - cz;
    for (int r = wave; r < 64; r += 4) {
        const int i2 = idx[row0 + r];
        const float* src = l1pts + ((size_t)b*512 + i2) * 128;
        buf[lane][r ^ lane]    = src[lane];
        buf[lane+64][r ^ lane] = src[lane + 64];
    }
    __syncthreads();
    const int oc0 = wave * 16;
    f32x2 aL[8], aH[8];
#pragma unroll
    for (int k = 0; k < 8; ++k) {
        const int j0 = oc0 + 2*k, j1 = oc0 + 2*k + 1;
        aL[k] = mk2(B0[j0]    + f0*Wt0[j0]     + f1*Wt0[128+j0]    + f2*Wt0[256+j0],
                    B0[j1]    + f0*Wt0[j1]     + f1*Wt0[128+j1]    + f2*Wt0[256+j1]);
        aH[k] = mk2(B0[64+j0] + f0*Wt0[64+j0]  + f1*Wt0[192+j0]    + f2*Wt0[320+j0],
                    B0[64+j1] + f0*Wt0[64+j1]  + f1*Wt0[192+j1]    + f2*Wt0[320+j1]);
    }
#pragma unroll 2
    for (int ci = 0; ci < 128; ++ci) {
        const float f = buf[ci][lane ^ (ci & 63)];
        const float* wp = Wt0 + (size_t)(ci+3)*128;
        fma16pk(aL, f, wp + oc0);
        fma16pk(aH, f, wp + 64 + oc0);
    }
    __syncthreads();
#pragma unroll
    for (int k = 0; k < 8; ++k) {
        buf[oc0+2*k][lane]      = fmaxf(aL[k].x, 0.f);
        buf[oc0+2*k+1][lane]    = fmaxf(aL[k].y, 0.f);
        buf[64+oc0+2*k][lane]   = fmaxf(aH[k].x, 0.f);
        buf[64+oc0+2*k+1][lane] = fmaxf(aH[k].y, 0.f);
    }
    __syncthreads();
#pragma unroll
    for (int k = 0; k < 8; ++k) {
        aL[k] = mk2(B1[oc0+2*k], B1[oc0+2*k+1]);
        aH[k] = mk2(B1[64+oc0+2*k], B1[64+oc0+2*k+1]);
    }
#pragma unroll 2
    for (int ci = 0; ci < 128; ++ci) {
        const float f = buf[ci][lane];
        const float* wp = Wt1 + (size_t)ci*128;
        fma16pk(aL, f, wp + oc0);
        fma16pk(aH, f, wp + 64 + oc0);
    }
    __syncthreads();
#pragma unroll
    for (int k = 0; k < 8; ++k) {
        buf[oc0+2*k][lane]      = fmaxf(aL[k].x, 0.f);
        buf[oc0+2*k+1][lane]    = fmaxf(aL[k].y, 0.f);
        buf[64+oc0+2*k][lane]   = fmaxf(aH[k].x, 0.f);
        buf[64+oc0+2*k+1][lane] = fmaxf(aH[k].y, 0.f);
    }
    __syncthreads();
    for (int half = 0; half < 2; ++half) {
        const int oc = half*128 + oc0;
#pragma unroll
        for (int k = 0; k < 8; ++k) {
            aL[k] = mk2(B2[oc+2*k], B2[oc+2*k+1]);
            aH[k] = mk2(B2[64+oc+2*k], B2[64+oc+2*k+1]);
        }
#pragma unroll 2
        for (int ci = 0; ci < 128; ++ci) {
            const float f = buf[ci][lane];
            const float* wp = Wt2 + (size_t)ci*256;
            fma16pk(aL, f, wp + oc);
            fma16pk(aH, f, wp + 64 + oc);
        }
#pragma unroll
        for (int k = 0; k < 8; ++k) {
            const float v0 = pool_full(fmaxf(aL[k].x, 0.f));
            const float v1 = pool_full(fmaxf(aL[k].y, 0.f));
            const float w0 = pool_full(fmaxf(aH[k].x, 0.f));
            const float w1 = pool_full(fmaxf(aH[k].y, 0.f));
            if (lane == 0) {
                pool[oc + 2*k]        = v0;
                pool[oc + 2*k + 1]    = v1;
                pool[64 + oc + 2*k]   = w0;
                pool[64 + oc + 2*k+1] = w1;
            }
        }
    }
    __syncthreads();
    // --- SA3 layer 1 for this group's single row: oc = tid ------------------
    {
        const int oc = tid;
        float acc = B30[oc] + cx*Wt30[0*256+oc] + cy*Wt30[1*256+oc] + cz*Wt30[2*256+oc];
#pragma unroll 8
        for (int ci = 0; ci < 256; ++ci)
            acc += pool[ci] * Wt30[(size_t)(ci+3)*256 + oc];
        outH1[(size_t)gblk*256 + oc] = fmaxf(acc, 0.f);
    }
}

// ---------------------------------------------------------------------------
// SA3 GEMM layers, packed-FMA accumulators. (unchanged)
// ---------------------------------------------------------------------------
template<int CIN, int COUT, bool CONCAT3, bool POOL>
__global__ __launch_bounds__(256)
void mlp_gemm_kernel(const float* __restrict__ inA, const float* __restrict__ inB,
                     const float* __restrict__ Wt, const float* __restrict__ Bb,
                     float* __restrict__ out)
{
    __shared__ float featS[128][64];
    const int tid = threadIdx.x, lane = tid & 63;
    const int wave = __builtin_amdgcn_readfirstlane(tid >> 6);
    const int row0 = blockIdx.x * 64;
    const int oc0 = blockIdx.y * 64 + wave * 16;
    f32x2 acc[8];
#pragma unroll
    for (int k = 0; k < 8; ++k) acc[k] = mk2(Bb[oc0+2*k], Bb[oc0+2*k+1]);
    for (int c0 = 0; c0 < CIN; c0 += 128) {
        const int csz = (CIN - c0 < 128) ? (CIN - c0) : 128;
        __syncthreads();
        for (int r = wave; r < 64; r += 4) {
            const int row = row0 + r;
            for (int cl = lane; cl < csz; cl += 64) {
                const int cig = c0 + cl;
                float v;
                if (CONCAT3)
                    v = (cig < 3) ? inA[(size_t)row*3 + cig]
                                  : inB[(size_t)row*(CIN-3) + (cig - 3)];
                else
                    v = inA[(size_t)row*CIN + cig];
                featS[cl][r ^ (cl & 63)] = v;
            }
        }
        __syncthreads();
        if (csz == 128) {
#pragma unroll 4
            for (int ci = 0; ci < 128; ++ci)
                fma16pk(acc, featS[ci][lane ^ (ci & 63)], Wt + (size_t)(c0+ci)*COUT + oc0);
        } else {
            for (int ci = 0; ci < csz; ++ci)
                fma16pk(acc, featS[ci][lane ^ (ci & 63)], Wt + (size_t)(c0+ci)*COUT + oc0);
        }
    }
    if (POOL) {
#pragma unroll
        for (int k = 0; k < 8; ++k) {
            const float v0 = pool_full(fmaxf(acc[k].x, 0.f));
            const float v1 = pool_full(fmaxf(acc[k].y, 0.f));
            if (lane == 0) {
                out[(size_t)blockIdx.x * COUT + oc0 + 2*k]     = v0;
                out[(size_t)blockIdx.x * COUT + oc0 + 2*k + 1] = v1;
            }
        }
    } else {
        float4 o0, o1, o2, o3;
        o0.x=fmaxf(acc[0].x,0.f); o0.y=fmaxf(acc[0].y,0.f); o0.z=fmaxf(acc[1].x,0.f); o0.w=fmaxf(acc[1].y,0.f);
        o1.x=fmaxf(acc[2].x,0.f); o1.y=fmaxf(acc[2].y,0.f); o1.z=fmaxf(acc[3].x,0.f); o1.w=fmaxf(acc[3].y,0.f);
        o2.x=fmaxf(acc[4].x,0.f); o2.y=fmaxf(acc[4].y,0.f); o2.z=fmaxf(acc[5].x,0.f); o2.w=fmaxf(acc[5].y,0.f);
        o3.x=fmaxf(acc[6].x,0.f); o3.y=fmaxf(acc[6].y,0.f); o3.z=fmaxf(acc[7].x,0.f); o3.w=fmaxf(acc[7].y,0.f);
        float4* op = (float4*)(out + (size_t)(row0 + lane)*COUT + oc0);
        op[0]=o0; op[1]=o1; op[2]=o2; op[3]=o3;
    }
}

// y[b][o] = fb[o] + max(pmax[2b], pmax[2b+1]) . fw[o]; one wave per output
__global__ __launch_bounds__(256)
void fc_kernel(const float* __restrict__ pmax, const float* __restrict__ fw,
               const float* __restrict__ fb, float* __restrict__ y)
{
    const int gw = (blockIdx.x * 256 + threadIdx.x) >> 6;
    const int lane = threadIdx.x & 63;
    const int b = gw >> 10, o = gw & 1023;
    const float4* g0 = (const float4*)(pmax + (size_t)(2*b) * 1024);
    const float4* g1 = (const float4*)(pmax + (size_t)(2*b+1) * 1024);
    const float4* wv = (const float4*)(fw + (size_t)o * 1024);
    float acc = 0.f;
#pragma unroll
    for (int r = 0; r < 4; ++r) {
        const float4 a = g0[lane + r*64];
        const float4 c = g1[lane + r*64];
        const float4 w = wv[lane + r*64];
        acc += fmaxf(a.x,c.x)*w.x + fmaxf(a.y,c.y)*w.y
             + fmaxf(a.z,c.z)*w.z + fmaxf(a.w,c.w)*w.w;
    }
#pragma unroll
    for (int m = 32; m >= 1; m >>= 1) acc += __shfl_xor(acc, m);
    if (lane == 0) y[gw] = acc + fb[o];
}

extern "C" void kernel_launch(void* const* d_in, const int* in_sizes, int n_in,
                              void* d_out, int out_size, void* d_ws, size_t ws_size,
                              hipStream_t stream)
{
    (void)in_sizes; (void)n_in; (void)out_size; (void)ws_size;
    const float* x   = (const float*)d_in[0];
    const float* s1w0 = (const float*)d_in[1];  const float* s1b0 = (const float*)d_in[2];
    const float* s1w1 = (const float*)d_in[3];  const float* s1b1 = (const float*)d_in[4];
    const float* s1w2 = (const float*)d_in[5];  const float* s1b2 = (const float*)d_in[6];
    const float* s2w0 = (const float*)d_in[7];  const float* s2b0 = (const float*)d_in[8];
    const float* s2w1 = (const float*)d_in[9];  const float* s2b1 = (const float*)d_in[10];
    const float* s2w2 = (const float*)d_in[11]; const float* s2b2 = (const float*)d_in[12];
    const float* s3w0 = (const float*)d_in[13]; const float* s3b0 = (const float*)d_in[14];
    const float* s3w1 = (const float*)d_in[15]; const float* s3b1 = (const float*)d_in[16];
    const float* s3w2 = (const float*)d_in[17]; const float* s3b2 = (const float*)d_in[18];
    const float* fw  = (const float*)d_in[19]; const float* fb  = (const float*)d_in[20];
    float* y = (float*)d_out;

    char* ws = (char*)d_ws;
    float* l1_xyz = (float*)(ws + 0);          // 16*512*3
    int*   idx1   = (int*)  (ws + 98304);      // 16*512*32
    float* l1_pts = (float*)(ws + 1146880);    // 16*512*128
    float* l2_xyz = (float*)(ws + 5341184);    // 16*128*3
    int*   idx2   = (int*)  (ws + 5365760);    // 16*128*64
    float* h1     = (float*)(ws + 7987200);    // 2048*256
    float* h2     = (float*)(ws + 10084352);   // 2048*512
    float* pmax   = (float*)(ws + 14278656);   // 32*1024 partial maxes
    float* wt1_0  = (float*)(ws + 14409728);   // [3][64]
    float* wt1_1  = (float*)(ws + 14410496);   // [64][64]
    float* wt1_2  = (float*)(ws + 14426880);   // [64][128]
    float* wt2_0  = (float*)(ws + 14459648);   // [131][128]
    float* wt2_1  = (float*)(ws + 14526720);   // [128][128]
    float* wt2_2  = (float*)(ws + 14592256);   // [128][256]
    float* wt3_0  = (float*)(ws + 14723328);   // [259][256]
    float* wt3_1  = (float*)(ws + 14988544);   // [256][512]
    float* wt3_2  = (float*)(ws + 15512832);   // [512][1024]

    const float r2_1 = (float)(0.2 * 0.2);
    const float r2_2 = (float)(0.4 * 0.4);

    fps_fused<4096, 512, 128, 256><<<BATCH + 3126, 256, 0, stream>>>(
        x, l1_xyz, l2_xyz,
        s1w0, wt1_0, s1w1, wt1_1, s1w2, wt1_2,
        s2w0, wt2_0, s2w1, wt2_1, s2w2, wt2_2,
        s3w0, wt3_0, s3w1, wt3_1, s3w2, wt3_2);
    ballq_both<<<(BATCH*512)/4 + (BATCH*128)/4, 256, 0, stream>>>(
        x, l1_xyz, idx1, r2_1, l1_xyz, l2_xyz, idx2, r2_2);
    sa1_fused<<<(BATCH*512*32)/64, 256, 0, stream>>>(x, l1_xyz, idx1,
        wt1_0, s1b0, wt1_1, s1b1, wt1_2, s1b2, l1_pts);
    sa2_fused<<<BATCH*128, 256, 0, stream>>>(l1_xyz, l1_pts, l2_xyz, idx2,
        wt2_0, s2b0, wt2_1, s2b1, wt2_2, s2b2, wt3_0, s3b0, h1);
    mlp_gemm_kernel<256, 512,  false, false><<<dim3(32, 8),  256, 0, stream>>>(h1, nullptr, wt3_1, s3b1, h2);
    mlp_gemm_kernel<512, 1024, false, true ><<<dim3(32, 16), 256, 0, stream>>>(h2, nullptr, wt3_2, s3b2, pmax);
    fc_kernel<<<(BATCH*1024)/4, 256, 0, stream>>>(pmax, fw, fb, y);
}

// Round 15
// 862.777 us; speedup vs baseline: 1.6885x; 1.0359x over previous
//
#include <hip/hip_runtime.h>

#ifndef BATCH
#define BATCH 16
#endif

typedef float f32x2 __attribute__((ext_vector_type(2)));
__device__ __forceinline__ f32x2 mk2(float a, float b) { f32x2 r; r.x = a; r.y = b; return r; }

// ---- DPP wave64 reduction helpers (row_shr scan + row_bcast merge) --------
template<int CTRL>
__device__ __forceinline__ float dppmaxf(float v)
{
    const int d = __builtin_amdgcn_update_dpp(__float_as_int(v), __float_as_int(v),
                                              CTRL, 0xf, 0xf, false);
    return fmaxf(v, __int_as_float(d));
}
template<int CTRL>
__device__ __forceinline__ unsigned dppminu(unsigned v)
{
    const unsigned d = (unsigned)__builtin_amdgcn_update_dpp((int)v, (int)v,
                                                             CTRL, 0xf, 0xf, false);
    return (d < v) ? d : v;
}
__device__ __forceinline__ float wave_max_bcast(float v)
{
    v = dppmaxf<0x111>(v);
    v = dppmaxf<0x112>(v);
    v = dppmaxf<0x114>(v);
    v = dppmaxf<0x118>(v);
    v = dppmaxf<0x142>(v);
    v = dppmaxf<0x143>(v);
    return __int_as_float(__builtin_amdgcn_readlane(__float_as_int(v), 63));
}
__device__ __forceinline__ unsigned wave_min_bcast(unsigned v)
{
    v = dppminu<0x111>(v);
    v = dppminu<0x112>(v);
    v = dppminu<0x114>(v);
    v = dppminu<0x118>(v);
    v = dppminu<0x142>(v);
    v = dppminu<0x143>(v);
    return (unsigned)__builtin_amdgcn_readlane((int)v, 63);
}

// ---- transpose body: W[O][C] -> Wt[C][O], flat index space ----------------
__device__ __forceinline__ void transpose_body(int blk, int tid,
    const float* __restrict__ s0, float* __restrict__ d0,
    const float* __restrict__ s1, float* __restrict__ d1,
    const float* __restrict__ s2, float* __restrict__ d2,
    const float* __restrict__ s3, float* __restrict__ d3,
    const float* __restrict__ s4, float* __restrict__ d4,
    const float* __restrict__ s5, float* __restrict__ d5,
    const float* __restrict__ s6, float* __restrict__ d6,
    const float* __restrict__ s7, float* __restrict__ d7,
    const float* __restrict__ s8, float* __restrict__ d8)
{
    int i = blk * 256 + tid;
    if (i < 192)    { d0[(i%3)  *64   + i/3  ] = s0[i]; return; }  i -= 192;
    if (i < 4096)   { d1[(i&63) *64   + (i>>6)] = s1[i]; return; } i -= 4096;
    if (i < 8192)   { d2[(i&63) *128  + (i>>6)] = s2[i]; return; } i -= 8192;
    if (i < 16768)  { d3[(i%131)*128  + i/131] = s3[i]; return; }  i -= 16768;
    if (i < 16384)  { d4[(i&127)*128  + (i>>7)] = s4[i]; return; } i -= 16384;
    if (i < 32768)  { d5[(i&127)*256  + (i>>7)] = s5[i]; return; } i -= 32768;
    if (i < 66304)  { d6[(i%259)*256  + i/259] = s6[i]; return; }  i -= 66304;
    if (i < 131072) { d7[(i&255)*512  + (i>>8)] = s7[i]; return; } i -= 131072;
    if (i < 524288) { d8[(i&511)*1024 + (i>>9)] = s8[i]; return; }
}

// ---------------------------------------------------------------------------
// Fused FPS (R10 variant) + weight-transpose blocks. (unchanged from R12)
// ---------------------------------------------------------------------------
template<int N, int NP1, int NP2, int BLOCK>
__global__ __launch_bounds__(BLOCK)
void fps_fused(const float* __restrict__ xyz,
               float* __restrict__ out1, float* __restrict__ out2,
               const float* __restrict__ ts0, float* __restrict__ td0,
               const float* __restrict__ ts1, float* __restrict__ td1,
               const float* __restrict__ ts2, float* __restrict__ td2,
               const float* __restrict__ ts3, float* __restrict__ td3,
               const float* __restrict__ ts4, float* __restrict__ td4,
               const float* __restrict__ ts5, float* __restrict__ td5,
               const float* __restrict__ ts6, float* __restrict__ td6,
               const float* __restrict__ ts7, float* __restrict__ td7,
               const float* __restrict__ ts8, float* __restrict__ td8)
{
#pragma clang fp contract(off)
    if ((int)blockIdx.x >= BATCH) {
        transpose_body(blockIdx.x - BATCH, threadIdx.x,
                       ts0, td0, ts1, td1, ts2, td2, ts3, td3, ts4, td4,
                       ts5, td5, ts6, td6, ts7, td7, ts8, td8);
        return;
    }
    constexpr int P  = N / BLOCK;
    constexpr int P2 = NP1 / BLOCK;
    constexpr int NW = BLOCK / 64;
    __shared__ float sx[N], sy[N], sz[N];
    __shared__ float s2x[NP1], s2y[NP1], s2z[NP1];
    __shared__ float o2x[NP2], o2y[NP2], o2z[NP2];
    __shared__ unsigned long long wslot[2][NW];
    const int b = blockIdx.x, t = threadIdx.x;
    const int lane = t & 63, wv = t >> 6;
    const float* xb = xyz + (size_t)b * N * 3;
    float px[P], py[P], pz[P], dist[P];
#pragma unroll
    for (int j = 0; j < P; ++j) {
        const int i = t + j * BLOCK;
        const float x = xb[i*3+0], y = xb[i*3+1], z = xb[i*3+2];
        sx[i] = x; sy[i] = y; sz[i] = z;
        px[j] = x; py[j] = y; pz[j] = z;
        dist[j] = 1e10f;
    }
    __syncthreads();
    float fx = sx[0], fy = sy[0], fz = sz[0];
    if (t == 0) { s2x[0] = fx; s2y[0] = fy; s2z[0] = fz; }
    for (int s = 1; s < NP1; ++s) {
        float bestv = -1.f; int besti = 0;
#pragma unroll
        for (int j = 0; j < P; ++j) {
            const float dx = px[j]-fx, dy = py[j]-fy, dz = pz[j]-fz;
            const float d = (dx*dx + dy*dy) + dz*dz;
            const float nd = fminf(dist[j], d);
            dist[j] = nd;
            if (nd > bestv) { bestv = nd; besti = t + j * BLOCK; }
        }
        const float wm = wave_max_bcast(bestv);
        const unsigned cand = (bestv == wm) ? (unsigned)besti : 0xffffffffu;
        const unsigned wi = wave_min_bcast(cand);
        const int par = s & 1;
        if (lane == 0)
            wslot[par][wv] = ((unsigned long long)__float_as_uint(wm) << 32)
                           | (unsigned)(~wi);
        __syncthreads();
        unsigned long long pa = wslot[par][0];
#pragma unroll
        for (int w = 1; w < NW; ++w) {
            const unsigned long long pb = wslot[par][w];
            pa = (pb > pa) ? pb : pa;
        }
        const int far = (int)(~(unsigned)pa);
        fx = sx[far]; fy = sy[far]; fz = sz[far];
        if (t == 0) { s2x[s] = fx; s2y[s] = fy; s2z[s] = fz; }
    }
    __syncthreads();
    // -------- stage 2 --------
    float mx[P2], my[P2], mz[P2], d2[P2];
#pragma unroll
    for (int j = 0; j < P2; ++j) {
        const int i = t + j * BLOCK;
        mx[j] = s2x[i]; my[j] = s2y[i]; mz[j] = s2z[i];
        d2[j] = 1e10f;
    }
    fx = s2x[0]; fy = s2y[0]; fz = s2z[0];
    if (t == 0) { o2x[0] = fx; o2y[0] = fy; o2z[0] = fz; }
    for (int s = 1; s < NP2; ++s) {
        float bestv = -1.f; int besti = 0;
#pragma unroll
        for (int j = 0; j < P2; ++j) {
            const float dx = mx[j]-fx, dy = my[j]-fy, dz = mz[j]-fz;
            const float d = (dx*dx + dy*dy) + dz*dz;
            const float nd = fminf(d2[j], d);
            d2[j] = nd;
            if (nd > bestv) { bestv = nd; besti = t + j * BLOCK; }
        }
        const float wm = wave_max_bcast(bestv);
        const unsigned cand = (bestv == wm) ? (unsigned)besti : 0xffffffffu;
        const unsigned wi = wave_min_bcast(cand);
        const int par = s & 1;
        if (lane == 0)
            wslot[par][wv] = ((unsigned long long)__float_as_uint(wm) << 32)
                           | (unsigned)(~wi);
        __syncthreads();
        unsigned long long pa = wslot[par][0];
#pragma unroll
        for (int w = 1; w < NW; ++w) {
            const unsigned long long pb = wslot[par][w];
            pa = (pb > pa) ? pb : pa;
        }
        const int far2 = (int)(~(unsigned)pa);
        fx = s2x[far2]; fy = s2y[far2]; fz = s2z[far2];
        if (t == 0) { o2x[s] = fx; o2y[s] = fy; o2z[s] = fz; }
    }
    __syncthreads();
    for (int i = t; i < NP1; i += BLOCK) {
        out1[((size_t)b*NP1 + i)*3 + 0] = s2x[i];
        out1[((size_t)b*NP1 + i)*3 + 1] = s2y[i];
        out1[((size_t)b*NP1 + i)*3 + 2] = s2z[i];
    }
    for (int i = t; i < NP2; i += BLOCK) {
        out2[((size_t)b*NP2 + i)*3 + 0] = o2x[i];
        out2[((size_t)b*NP2 + i)*3 + 1] = o2y[i];
        out2[((size_t)b*NP2 + i)*3 + 2] = o2z[i];
    }
}

// ---- inline ball-query scan: ONE wave scans one query, indices -> LDS -----
template<int N, int K>
__device__ __forceinline__ void ballq_scan_lds(const float* __restrict__ xb,
                                               const float qx, const float qy,
                                               const float qz, const float r2,
                                               int* __restrict__ sidx,
                                               const int lane)
{
#pragma clang fp contract(off)
    int base = 0, first = -1;
    for (int c = 0; c < N; c += 64) {
        const int i = c + lane;
        const float dx = xb[i*3+0]-qx, dy = xb[i*3+1]-qy, dz = xb[i*3+2]-qz;
        const float d = (dx*dx + dy*dy) + dz*dz;
        const bool hit = !(d > r2);
        const unsigned long long m = __ballot(hit);
        if (first < 0 && m) first = c + __builtin_ctzll(m);
        const int pos = base + __popcll(m & ((1ull << lane) - 1ull));
        if (hit && pos < K) sidx[pos] = i;
        base += __popcll(m);
        if (base >= K) break;
    }
    if (base < K && lane >= base && lane < K) sidx[lane] = first;
}

// 8 packed FMAs against 16 contiguous transposed weights (bit-identical).
__device__ __forceinline__ void fma16pk(f32x2 (&acc)[8], const float f,
                                        const float* __restrict__ wrow)
{
    const float4 w0 = ((const float4*)wrow)[0];
    const float4 w1 = ((const float4*)wrow)[1];
    const float4 w2 = ((const float4*)wrow)[2];
    const float4 w3 = ((const float4*)wrow)[3];
    const f32x2 ff = mk2(f, f);
    acc[0] += ff * mk2(w0.x, w0.y);
    acc[1] += ff * mk2(w0.z, w0.w);
    acc[2] += ff * mk2(w1.x, w1.y);
    acc[3] += ff * mk2(w1.z, w1.w);
    acc[4] += ff * mk2(w2.x, w2.y);
    acc[5] += ff * mk2(w2.z, w2.w);
    acc[6] += ff * mk2(w3.x, w3.y);
    acc[7] += ff * mk2(w3.z, w3.w);
}

__device__ __forceinline__ float pool_half(float v)
{
    v = fmaxf(v, __shfl_xor(v, 1));
    v = fmaxf(v, __shfl_xor(v, 2));
    v = fmaxf(v, __shfl_xor(v, 4));
    v = fmaxf(v, __shfl_xor(v, 8));
    v = fmaxf(v, __shfl_xor(v, 16));
    return v;
}
__device__ __forceinline__ float pool_full(float v)
{
    v = pool_half(v);
    return fmaxf(v, __shfl_xor(v, 32));
}

// ---------------------------------------------------------------------------
// SA1 fused + inline ball query. Block owns 64 rows = 2 groups of K=32.
// Waves 0/1 scan the 2 queries (indices to LDS), barrier, then the R12
// in-place 16 KB MLP pipeline (unchanged math).
// ---------------------------------------------------------------------------
__global__ __launch_bounds__(256)
void sa1_fused(const float* __restrict__ xyz, const float* __restrict__ nxyz,
               const float r2,
               const float* __restrict__ Wt0, const float* __restrict__ B0,
               const float* __restrict__ Wt1, const float* __restrict__ B1,
               const float* __restrict__ Wt2, const float* __restrict__ B2,
               float* __restrict__ out)
{
    __shared__ float buf[64][64];
    __shared__ int sidx[64];
    const int tid = threadIdx.x, lane = tid & 63;
    const int wave = __builtin_amdgcn_readfirstlane(tid >> 6);
    const int row0 = blockIdx.x * 64;
    const int g0 = row0 >> 5;                 // first of 2 groups
    const int b = g0 >> 9;
    const float* xb = xyz + (size_t)b * 4096 * 3;
    if (wave < 2) {
        const int g = g0 + wave;
        ballq_scan_lds<4096, 32>(xb,
            nxyz[(size_t)g*3 + 0], nxyz[(size_t)g*3 + 1], nxyz[(size_t)g*3 + 2],
            r2, sidx + wave*32, lane);
    }
    __syncthreads();
    const int g = g0 + (lane >> 5);
    const int i = sidx[lane];
    const float* p = xb + (size_t)i * 3;
    const float f0 = p[0] - nxyz[(size_t)g*3 + 0];
    const float f1 = p[1] - nxyz[(size_t)g*3 + 1];
    const float f2 = p[2] - nxyz[(size_t)g*3 + 2];
    const int oc0 = wave * 16;
    f32x2 aL[8], aH[8];
#pragma unroll
    for (int j = 0; j < 16; ++j) {
        const float v = B0[oc0+j] + f0*Wt0[0*64+oc0+j] + f1*Wt0[1*64+oc0+j] + f2*Wt0[2*64+oc0+j];
        buf[oc0+j][lane] = fmaxf(v, 0.f);
    }
    __syncthreads();
#pragma unroll
    for (int k = 0; k < 8; ++k) aL[k] = mk2(B1[oc0+2*k], B1[oc0+2*k+1]);
#pragma unroll 4
    for (int ci = 0; ci < 64; ++ci)
        fma16pk(aL, buf[ci][lane], Wt1 + ci*64 + oc0);
    __syncthreads();
#pragma unroll
    for (int k = 0; k < 8; ++k) {
        buf[oc0+2*k][lane]   = fmaxf(aL[k].x, 0.f);
        buf[oc0+2*k+1][lane] = fmaxf(aL[k].y, 0.f);
    }
    __syncthreads();
#pragma unroll
    for (int k = 0; k < 8; ++k) {
        aL[k] = mk2(B2[oc0+2*k], B2[oc0+2*k+1]);
        aH[k] = mk2(B2[64+oc0+2*k], B2[64+oc0+2*k+1]);
    }
#pragma unroll 2
    for (int ci = 0; ci < 64; ++ci) {
        const float f = buf[ci][lane];
        fma16pk(aL, f, Wt2 + ci*128 + oc0);
        fma16pk(aH, f, Wt2 + ci*128 + 64 + oc0);
    }
#pragma unroll
    for (int k = 0; k < 8; ++k) {
        const float v0 = pool_half(fmaxf(aL[k].x, 0.f));
        const float v1 = pool_half(fmaxf(aL[k].y, 0.f));
        const float w0 = pool_half(fmaxf(aH[k].x, 0.f));
        const float w1 = pool_half(fmaxf(aH[k].y, 0.f));
        if ((lane & 31) == 0) {
            const size_t orow = (size_t)((row0 + lane) >> 5) * 128;
            out[orow + oc0 + 2*k]       = v0;
            out[orow + oc0 + 2*k + 1]   = v1;
            out[orow + 64 + oc0 + 2*k]     = w0;
            out[orow + 64 + oc0 + 2*k + 1] = w1;
        }
    }
}

// ---------------------------------------------------------------------------
// SA2 fused + inline ball query + SA3-L1 + SA3-L2 epilogues. Block owns one
// group (64 rows). Wave 0 scans the query (K=64, LDS), then the R14 MLP
// pipeline; epilogue computes h1row[256] (ci ascending like old
// mlp_gemm<259,256,CONCAT3>) then h2row[512] (ci ascending like old
// mlp_gemm<256,512>) -> bit-identical chains. Writes only h2.
// ---------------------------------------------------------------------------
__global__ __launch_bounds__(256)
void sa2_fused(const float* __restrict__ l1xyz, const float* __restrict__ l1pts,
               const float* __restrict__ nxyz, const float r2,
               const float* __restrict__ Wt0, const float* __restrict__ B0,
               const float* __restrict__ Wt1, const float* __restrict__ B1,
               const float* __restrict__ Wt2, const float* __restrict__ B2,
               const float* __restrict__ Wt30, const float* __restrict__ B30,
               const float* __restrict__ Wt31, const float* __restrict__ B31,
               float* __restrict__ outH2)
{
    __shared__ float buf[128][64];
    __shared__ float pool[256];
    __shared__ float h1s[256];
    __shared__ int sidx[64];
    const int tid = threadIdx.x, lane = tid & 63;
    const int wave = __builtin_amdgcn_readfirstlane(tid >> 6);
    const int gblk = blockIdx.x;
    const int b = gblk >> 7;
    const float cx = nxyz[(size_t)gblk*3 + 0];
    const float cy = nxyz[(size_t)gblk*3 + 1];
    const float cz = nxyz[(size_t)gblk*3 + 2];
    const float* xb = l1xyz + (size_t)b * 512 * 3;
    if (wave == 0)
        ballq_scan_lds<512, 64>(xb, cx, cy, cz, r2, sidx, lane);
    __syncthreads();
    const int myi = sidx[lane];
    const float* pc = xb + (size_t)myi * 3;
    const float f0 = pc[0] - cx;
    const float f1 = pc[1] - cy;
    const float f2 = pc[2] - cz;
    for (int r = wave; r < 64; r += 4) {
        const int i2 = sidx[r];
        const float* src = l1pts + ((size_t)b*512 + i2) * 128;
        buf[lane][r ^ lane]    = src[lane];
        buf[lane+64][r ^ lane] = src[lane + 64];
    }
    __syncthreads();
    const int oc0 = wave * 16;
    f32x2 aL[8], aH[8];
#pragma unroll
    for (int k = 0; k < 8; ++k) {
        const int j0 = oc0 + 2*k, j1 = oc0 + 2*k + 1;
        aL[k] = mk2(B0[j0]    + f0*Wt0[j0]     + f1*Wt0[128+j0]    + f2*Wt0[256+j0],
                    B0[j1]    + f0*Wt0[j1]     + f1*Wt0[128+j1]    + f2*Wt0[256+j1]);
        aH[k] = mk2(B0[64+j0] + f0*Wt0[64+j0]  + f1*Wt0[192+j0]    + f2*Wt0[320+j0],
                    B0[64+j1] + f0*Wt0[64+j1]  + f1*Wt0[192+j1]    + f2*Wt0[320+j1]);
    }
#pragma unroll 2
    for (int ci = 0; ci < 128; ++ci) {
        const float f = buf[ci][lane ^ (ci & 63)];
        const float* wp = Wt0 + (size_t)(ci+3)*128;
        fma16pk(aL, f, wp + oc0);
        fma16pk(aH, f, wp + 64 + oc0);
    }
    __syncthreads();
#pragma unroll
    for (int k = 0; k < 8; ++k) {
        buf[oc0+2*k][lane]      = fmaxf(aL[k].x, 0.f);
        buf[oc0+2*k+1][lane]    = fmaxf(aL[k].y, 0.f);
        buf[64+oc0+2*k][lane]   = fmaxf(aH[k].x, 0.f);
        buf[64+oc0+2*k+1][lane] = fmaxf(aH[k].y, 0.f);
    }
    __syncthreads();
#pragma unroll
    for (int k = 0; k < 8; ++k) {
        aL[k] = mk2(B1[oc0+2*k], B1[oc0+2*k+1]);
        aH[k] = mk2(B1[64+oc0+2*k], B1[64+oc0+2*k+1]);
    }
#pragma unroll 2
    for (int ci = 0; ci < 128; ++ci) {
        const float f = buf[ci][lane];
        const float* wp = Wt1 + (size_t)ci*128;
        fma16pk(aL, f, wp + oc0);
        fma16pk(aH, f, wp + 64 + oc0);
    }
    __syncthreads();
#pragma unroll
    for (int k = 0; k < 8; ++k) {
        buf[oc0+2*k][lane]      = fmaxf(aL[k].x, 0.f);
        buf[oc0+2*k+1][lane]    = fmaxf(aL[k].y, 0.f);
        buf[64+oc0+2*k][lane]   = fmaxf(aH[k].x, 0.f);
        buf[64+oc0+2*k+1][lane] = fmaxf(aH[k].y, 0.f);
    }
    __syncthreads();
    for (int half = 0; half < 2; ++half) {
        const int oc = half*128 + oc0;
#pragma unroll
        for (int k = 0; k < 8; ++k) {
            aL[k] = mk2(B2[oc+2*k], B2[oc+2*k+1]);
            aH[k] = mk2(B2[64+oc+2*k], B2[64+oc+2*k+1]);
        }
#pragma unroll 2
        for (int ci = 0; ci < 128; ++ci) {
            const float f = buf[ci][lane];
            const float* wp = Wt2 + (size_t)ci*256;
            fma16pk(aL, f, wp + oc);
            fma16pk(aH, f, wp + 64 + oc);
        }
#pragma unroll
        for (int k = 0; k < 8; ++k) {
            const float v0 = pool_full(fmaxf(aL[k].x, 0.f));
            const float v1 = pool_full(fmaxf(aL[k].y, 0.f));
            const float w0 = pool_full(fmaxf(aH[k].x, 0.f));
            const float w1 = pool_full(fmaxf(aH[k].y, 0.f));
            if (lane == 0) {
                pool[oc + 2*k]        = v0;
                pool[oc + 2*k + 1]    = v1;
                pool[64 + oc + 2*k]   = w0;
                pool[64 + oc + 2*k+1] = w1;
            }
        }
    }
    __syncthreads();
    // --- SA3 layer 1 for this group's row: oc = tid -------------------------
    {
        float acc = B30[tid] + cx*Wt30[0*256+tid] + cy*Wt30[1*256+tid] + cz*Wt30[2*256+tid];
#pragma unroll 8
        for (int ci = 0; ci < 256; ++ci)
            acc += pool[ci] * Wt30[(size_t)(ci+3)*256 + tid];
        h1s[tid] = fmaxf(acc, 0.f);
    }
    __syncthreads();
    // --- SA3 layer 2 for this row: 2 ocs per thread -------------------------
    {
        float a0 = B31[tid], a1 = B31[256 + tid];
#pragma unroll 8
        for (int ci = 0; ci < 256; ++ci) {
            const float f = h1s[ci];
            a0 += f * Wt31[(size_t)ci*512 + tid];
            a1 += f * Wt31[(size_t)ci*512 + 256 + tid];
        }
        outH2[(size_t)gblk*512 + tid]       = fmaxf(a0, 0.f);
        outH2[(size_t)gblk*512 + 256 + tid] = fmaxf(a1, 0.f);
    }
}

// ---------------------------------------------------------------------------
// SA3 GEMM layer (only <512,1024,POOL> used now), packed-FMA accumulators.
// ---------------------------------------------------------------------------
template<int CIN, int COUT, bool CONCAT3, bool POOL>
__global__ __launch_bounds__(256)
void mlp_gemm_kernel(const float* __restrict__ inA, const float* __restrict__ inB,
                     const float* __restrict__ Wt, const float* __restrict__ Bb,
                     float* __restrict__ out)
{
    __shared__ float featS[128][64];
    const int tid = threadIdx.x, lane = tid & 63;
    const int wave = __builtin_amdgcn_readfirstlane(tid >> 6);
    const int row0 = blockIdx.x * 64;
    const int oc0 = blockIdx.y * 64 + wave * 16;
    f32x2 acc[8];
#pragma unroll
    for (int k = 0; k < 8; ++k) acc[k] = mk2(Bb[oc0+2*k], Bb[oc0+2*k+1]);
    for (int c0 = 0; c0 < CIN; c0 += 128) {
        const int csz = (CIN - c0 < 128) ? (CIN - c0) : 128;
        __syncthreads();
        for (int r = wave; r < 64; r += 4) {
            const int row = row0 + r;
            for (int cl = lane; cl < csz; cl += 64) {
                const int cig = c0 + cl;
                float v;
                if (CONCAT3)
                    v = (cig < 3) ? inA[(size_t)row*3 + cig]
                                  : inB[(size_t)row*(CIN-3) + (cig - 3)];
                else
                    v = inA[(size_t)row*CIN + cig];
                featS[cl][r ^ (cl & 63)] = v;
            }
        }
        __syncthreads();
        if (csz == 128) {
#pragma unroll 4
            for (int ci = 0; ci < 128; ++ci)
                fma16pk(acc, featS[ci][lane ^ (ci & 63)], Wt + (size_t)(c0+ci)*COUT + oc0);
        } else {
            for (int ci = 0; ci < csz; ++ci)
                fma16pk(acc, featS[ci][lane ^ (ci & 63)], Wt + (size_t)(c0+ci)*COUT + oc0);
        }
    }
    if (POOL) {
#pragma unroll
        for (int k = 0; k < 8; ++k) {
            const float v0 = pool_full(fmaxf(acc[k].x, 0.f));
            const float v1 = pool_full(fmaxf(acc[k].y, 0.f));
            if (lane == 0) {
                out[(size_t)blockIdx.x * COUT + oc0 + 2*k]     = v0;
                out[(size_t)blockIdx.x * COUT + oc0 + 2*k + 1] = v1;
            }
        }
    } else {
        float4 o0, o1, o2, o3;
        o0.x=fmaxf(acc[0].x,0.f); o0.y=fmaxf(acc[0].y,0.f); o0.z=fmaxf(acc[1].x,0.f); o0.w=fmaxf(acc[1].y,0.f);
        o1.x=fmaxf(acc[2].x,0.f); o1.y=fmaxf(acc[2].y,0.f); o1.z=fmaxf(acc[3].x,0.f); o1.w=fmaxf(acc[3].y,0.f);
        o2.x=fmaxf(acc[4].x,0.f); o2.y=fmaxf(acc[4].y,0.f); o2.z=fmaxf(acc[5].x,0.f); o2.w=fmaxf(acc[5].y,0.f);
        o3.x=fmaxf(acc[6].x,0.f); o3.y=fmaxf(acc[6].y,0.f); o3.z=fmaxf(acc[7].x,0.f); o3.w=fmaxf(acc[7].y,0.f);
        float4* op = (float4*)(out + (size_t)(row0 + lane)*COUT + oc0);
        op[0]=o0; op[1]=o1; op[2]=o2; op[3]=o3;
    }
}

// y[b][o] = fb[o] + max(pmax[2b], pmax[2b+1]) . fw[o]; one wave per output
__global__ __launch_bounds__(256)
void fc_kernel(const float* __restrict__ pmax, const float* __restrict__ fw,
               const float* __restrict__ fb, float* __restrict__ y)
{
    const int gw = (blockIdx.x * 256 + threadIdx.x) >> 6;
    const int lane = threadIdx.x & 63;
    const int b = gw >> 10, o = gw & 1023;
    const float4* g0 = (const float4*)(pmax + (size_t)(2*b) * 1024);
    const float4* g1 = (const float4*)(pmax + (size_t)(2*b+1) * 1024);
    const float4* wv = (const float4*)(fw + (size_t)o * 1024);
    float acc = 0.f;
#pragma unroll
    for (int r = 0; r < 4; ++r) {
        const float4 a = g0[lane + r*64];
        const float4 c = g1[lane + r*64];
        const float4 w = wv[lane + r*64];
        acc += fmaxf(a.x,c.x)*w.x + fmaxf(a.y,c.y)*w.y
             + fmaxf(a.z,c.z)*w.z + fmaxf(a.w,c.w)*w.w;
    }
#pragma unroll
    for (int m = 32; m >= 1; m >>= 1) acc += __shfl_xor(acc, m);
    if (lane == 0) y[gw] = acc + fb[o];
}

extern "C" void kernel_launch(void* const* d_in, const int* in_sizes, int n_in,
                              void* d_out, int out_size, void* d_ws, size_t ws_size,
                              hipStream_t stream)
{
    (void)in_sizes; (void)n_in; (void)out_size; (void)ws_size;
    const float* x   = (const float*)d_in[0];
    const float* s1w0 = (const float*)d_in[1];  const float* s1b0 = (const float*)d_in[2];
    const float* s1w1 = (const float*)d_in[3];  const float* s1b1 = (const float*)d_in[4];
    const float* s1w2 = (const float*)d_in[5];  const float* s1b2 = (const float*)d_in[6];
    const float* s2w0 = (const float*)d_in[7];  const float* s2b0 = (const float*)d_in[8];
    const float* s2w1 = (const float*)d_in[9];  const float* s2b1 = (const float*)d_in[10];
    const float* s2w2 = (const float*)d_in[11]; const float* s2b2 = (const float*)d_in[12];
    const float* s3w0 = (const float*)d_in[13]; const float* s3b0 = (const float*)d_in[14];
    const float* s3w1 = (const float*)d_in[15]; const float* s3b1 = (const float*)d_in[16];
    const float* s3w2 = (const float*)d_in[17]; const float* s3b2 = (const float*)d_in[18];
    const float* fw  = (const float*)d_in[19]; const float* fb  = (const float*)d_in[20];
    float* y = (float*)d_out;

    char* ws = (char*)d_ws;
    float* l1_xyz = (float*)(ws + 0);          // 16*512*3
    float* l1_pts = (float*)(ws + 1146880);    // 16*512*128
    float* l2_xyz = (float*)(ws + 5341184);    // 16*128*3
    float* h2     = (float*)(ws + 10084352);   // 2048*512
    float* pmax   = (float*)(ws + 14278656);   // 32*1024 partial maxes
    float* wt1_0  = (float*)(ws + 14409728);   // [3][64]
    float* wt1_1  = (float*)(ws + 14410496);   // [64][64]
    float* wt1_2  = (float*)(ws + 14426880);   // [64][128]
    float* wt2_0  = (float*)(ws + 14459648);   // [131][128]
    float* wt2_1  = (float*)(ws + 14526720);   // [128][128]
    float* wt2_2  = (float*)(ws + 14592256);   // [128][256]
    float* wt3_0  = (float*)(ws + 14723328);   // [259][256]
    float* wt3_1  = (float*)(ws + 14988544);   // [256][512]
    float* wt3_2  = (float*)(ws + 15512832);   // [512][1024]

    const float r2_1 = (float)(0.2 * 0.2);
    const float r2_2 = (float)(0.4 * 0.4);

    fps_fused<4096, 512, 128, 256><<<BATCH + 3126, 256, 0, stream>>>(
        x, l1_xyz, l2_xyz,
        s1w0, wt1_0, s1w1, wt1_1, s1w2, wt1_2,
        s2w0, wt2_0, s2w1, wt2_1, s2w2, wt2_2,
        s3w0, wt3_0, s3w1, wt3_1, s3w2, wt3_2);
    sa1_fused<<<(BATCH*512*32)/64, 256, 0, stream>>>(x, l1_xyz, r2_1,
        wt1_0, s1b0, wt1_1, s1b1, wt1_2, s1b2, l1_pts);
    sa2_fused<<<BATCH*128, 256, 0, stream>>>(l1_xyz, l1_pts, l2_xyz, r2_2,
        wt2_0, s2b0, wt2_1, s2b1, wt2_2, s2b2,
        wt3_0, s3b0, wt3_1, s3b1, h2);
    mlp_gemm_kernel<512, 1024, false, true ><<<dim3(32, 16), 256, 0, stream>>>(h2, nullptr, wt3_2, s3b2, pmax);
    fc_kernel<<<(BATCH*1024)/4, 256, 0, stream>>>(pmax, fw, fb, y);
}

// Round 16
// 820.104 us; speedup vs baseline: 1.7764x; 1.0520x over previous
//
#include <hip/hip_runtime.h>

#ifndef BATCH
#define BATCH 16
#endif

typedef float f32x2 __attribute__((ext_vector_type(2)));
__device__ __forceinline__ f32x2 mk2(float a, float b) { f32x2 r; r.x = a; r.y = b; return r; }

// ---- DPP wave64 reduction helpers (row_shr scan + row_bcast merge) --------
template<int CTRL>
__device__ __forceinline__ float dppmaxf(float v)
{
    const int d = __builtin_amdgcn_update_dpp(__float_as_int(v), __float_as_int(v),
                                              CTRL, 0xf, 0xf, false);
    return fmaxf(v, __int_as_float(d));
}
template<int CTRL>
__device__ __forceinline__ unsigned dppminu(unsigned v)
{
    const unsigned d = (unsigned)__builtin_amdgcn_update_dpp((int)v, (int)v,
                                                             CTRL, 0xf, 0xf, false);
    return (d < v) ? d : v;
}
__device__ __forceinline__ float wave_max_bcast(float v)
{
    v = dppmaxf<0x111>(v);
    v = dppmaxf<0x112>(v);
    v = dppmaxf<0x114>(v);
    v = dppmaxf<0x118>(v);
    v = dppmaxf<0x142>(v);
    v = dppmaxf<0x143>(v);
    return __int_as_float(__builtin_amdgcn_readlane(__float_as_int(v), 63));
}
__device__ __forceinline__ unsigned wave_min_bcast(unsigned v)
{
    v = dppminu<0x111>(v);
    v = dppminu<0x112>(v);
    v = dppminu<0x114>(v);
    v = dppminu<0x118>(v);
    v = dppminu<0x142>(v);
    v = dppminu<0x143>(v);
    return (unsigned)__builtin_amdgcn_readlane((int)v, 63);
}

// ---- transpose body: W[O][C] -> Wt[C][O], flat index space ----------------
__device__ __forceinline__ void transpose_body(int blk, int tid,
    const float* __restrict__ s0, float* __restrict__ d0,
    const float* __restrict__ s1, float* __restrict__ d1,
    const float* __restrict__ s2, float* __restrict__ d2,
    const float* __restrict__ s3, float* __restrict__ d3,
    const float* __restrict__ s4, float* __restrict__ d4,
    const float* __restrict__ s5, float* __restrict__ d5,
    const float* __restrict__ s6, float* __restrict__ d6,
    const float* __restrict__ s7, float* __restrict__ d7,
    const float* __restrict__ s8, float* __restrict__ d8)
{
    int i = blk * 256 + tid;
    if (i < 192)    { d0[(i%3)  *64   + i/3  ] = s0[i]; return; }  i -= 192;
    if (i < 4096)   { d1[(i&63) *64   + (i>>6)] = s1[i]; return; } i -= 4096;
    if (i < 8192)   { d2[(i&63) *128  + (i>>6)] = s2[i]; return; } i -= 8192;
    if (i < 16768)  { d3[(i%131)*128  + i/131] = s3[i]; return; }  i -= 16768;
    if (i < 16384)  { d4[(i&127)*128  + (i>>7)] = s4[i]; return; } i -= 16384;
    if (i < 32768)  { d5[(i&127)*256  + (i>>7)] = s5[i]; return; } i -= 32768;
    if (i < 66304)  { d6[(i%259)*256  + i/259] = s6[i]; return; }  i -= 66304;
    if (i < 131072) { d7[(i&255)*512  + (i>>8)] = s7[i]; return; } i -= 131072;
    if (i < 524288) { d8[(i&511)*1024 + (i>>9)] = s8[i]; return; }
}

// ---------------------------------------------------------------------------
// FPS stage 1 only (4096 -> 512) + weight-transpose blocks.
// Identical step math to the R12 fps_fused stage 1.
// ---------------------------------------------------------------------------
template<int N, int NP1, int BLOCK>
__global__ __launch_bounds__(BLOCK)
void fps1_fused(const float* __restrict__ xyz, float* __restrict__ out1,
                const float* __restrict__ ts0, float* __restrict__ td0,
                const float* __restrict__ ts1, float* __restrict__ td1,
                const float* __restrict__ ts2, float* __restrict__ td2,
                const float* __restrict__ ts3, float* __restrict__ td3,
                const float* __restrict__ ts4, float* __restrict__ td4,
                const float* __restrict__ ts5, float* __restrict__ td5,
                const float* __restrict__ ts6, float* __restrict__ td6,
                const float* __restrict__ ts7, float* __restrict__ td7,
                const float* __restrict__ ts8, float* __restrict__ td8)
{
#pragma clang fp contract(off)
    if ((int)blockIdx.x >= BATCH) {
        transpose_body(blockIdx.x - BATCH, threadIdx.x,
                       ts0, td0, ts1, td1, ts2, td2, ts3, td3, ts4, td4,
                       ts5, td5, ts6, td6, ts7, td7, ts8, td8);
        return;
    }
    constexpr int P  = N / BLOCK;
    constexpr int NW = BLOCK / 64;
    __shared__ float sx[N], sy[N], sz[N];
    __shared__ float s2x[NP1], s2y[NP1], s2z[NP1];
    __shared__ unsigned long long wslot[2][NW];
    const int b = blockIdx.x, t = threadIdx.x;
    const int lane = t & 63, wv = t >> 6;
    const float* xb = xyz + (size_t)b * N * 3;
    float px[P], py[P], pz[P], dist[P];
#pragma unroll
    for (int j = 0; j < P; ++j) {
        const int i = t + j * BLOCK;
        const float x = xb[i*3+0], y = xb[i*3+1], z = xb[i*3+2];
        sx[i] = x; sy[i] = y; sz[i] = z;
        px[j] = x; py[j] = y; pz[j] = z;
        dist[j] = 1e10f;
    }
    __syncthreads();
    float fx = sx[0], fy = sy[0], fz = sz[0];
    if (t == 0) { s2x[0] = fx; s2y[0] = fy; s2z[0] = fz; }
    for (int s = 1; s < NP1; ++s) {
        float bestv = -1.f; int besti = 0;
#pragma unroll
        for (int j = 0; j < P; ++j) {
            const float dx = px[j]-fx, dy = py[j]-fy, dz = pz[j]-fz;
            const float d = (dx*dx + dy*dy) + dz*dz;
            const float nd = fminf(dist[j], d);
            dist[j] = nd;
            if (nd > bestv) { bestv = nd; besti = t + j * BLOCK; }
        }
        const float wm = wave_max_bcast(bestv);
        const unsigned cand = (bestv == wm) ? (unsigned)besti : 0xffffffffu;
        const unsigned wi = wave_min_bcast(cand);
        const int par = s & 1;
        if (lane == 0)
            wslot[par][wv] = ((unsigned long long)__float_as_uint(wm) << 32)
                           | (unsigned)(~wi);
        __syncthreads();
        unsigned long long pa = wslot[par][0];
#pragma unroll
        for (int w = 1; w < NW; ++w) {
            const unsigned long long pb = wslot[par][w];
            pa = (pb > pa) ? pb : pa;
        }
        const int far = (int)(~(unsigned)pa);
        fx = sx[far]; fy = sy[far]; fz = sz[far];
        if (t == 0) { s2x[s] = fx; s2y[s] = fy; s2z[s] = fz; }
    }
    __syncthreads();
    for (int i = t; i < NP1; i += BLOCK) {
        out1[((size_t)b*NP1 + i)*3 + 0] = s2x[i];
        out1[((size_t)b*NP1 + i)*3 + 1] = s2y[i];
        out1[((size_t)b*NP1 + i)*3 + 2] = s2z[i];
    }
}

// ---- inline ball-query scan: ONE wave scans one query, indices -> LDS -----
template<int N, int K>
__device__ __forceinline__ void ballq_scan_lds(const float* __restrict__ xb,
                                               const float qx, const float qy,
                                               const float qz, const float r2,
                                               int* __restrict__ sidx,
                                               const int lane)
{
#pragma clang fp contract(off)
    int base = 0, first = -1;
    for (int c = 0; c < N; c += 64) {
        const int i = c + lane;
        const float dx = xb[i*3+0]-qx, dy = xb[i*3+1]-qy, dz = xb[i*3+2]-qz;
        const float d = (dx*dx + dy*dy) + dz*dz;
        const bool hit = !(d > r2);
        const unsigned long long m = __ballot(hit);
        if (first < 0 && m) first = c + __builtin_ctzll(m);
        const int pos = base + __popcll(m & ((1ull << lane) - 1ull));
        if (hit && pos < K) sidx[pos] = i;
        base += __popcll(m);
        if (base >= K) break;
    }
    if (base < K && lane >= base && lane < K) sidx[lane] = first;
}

// 8 packed FMAs against 16 contiguous transposed weights (bit-identical).
__device__ __forceinline__ void fma16pk(f32x2 (&acc)[8], const float f,
                                        const float* __restrict__ wrow)
{
    const float4 w0 = ((const float4*)wrow)[0];
    const float4 w1 = ((const float4*)wrow)[1];
    const float4 w2 = ((const float4*)wrow)[2];
    const float4 w3 = ((const float4*)wrow)[3];
    const f32x2 ff = mk2(f, f);
    acc[0] += ff * mk2(w0.x, w0.y);
    acc[1] += ff * mk2(w0.z, w0.w);
    acc[2] += ff * mk2(w1.x, w1.y);
    acc[3] += ff * mk2(w1.z, w1.w);
    acc[4] += ff * mk2(w2.x, w2.y);
    acc[5] += ff * mk2(w2.z, w2.w);
    acc[6] += ff * mk2(w3.x, w3.y);
    acc[7] += ff * mk2(w3.z, w3.w);
}

__device__ __forceinline__ float pool_half(float v)
{
    v = fmaxf(v, __shfl_xor(v, 1));
    v = fmaxf(v, __shfl_xor(v, 2));
    v = fmaxf(v, __shfl_xor(v, 4));
    v = fmaxf(v, __shfl_xor(v, 8));
    v = fmaxf(v, __shfl_xor(v, 16));
    return v;
}
__device__ __forceinline__ float pool_full(float v)
{
    v = pool_half(v);
    return fmaxf(v, __shfl_xor(v, 32));
}

// ---------------------------------------------------------------------------
// K2: blocks [0,BATCH) run FPS stage 2 (512 -> 128, reading l1_xyz from
// global — bit-identical values to the old in-LDS stage 2); blocks
// [BATCH, ...) run SA1 (+inline ball query). The two paths are independent
// (both depend only on K1's l1_xyz) and share a 16.6 KB LDS carve.
// ---------------------------------------------------------------------------
template<int NP1, int NP2, int BLOCK>
__global__ __launch_bounds__(BLOCK)
void fps2_sa1(const float* __restrict__ xyz, const float* __restrict__ l1xyz,
              float* __restrict__ out2, const float r2,
              const float* __restrict__ Wt0, const float* __restrict__ B0,
              const float* __restrict__ Wt1, const float* __restrict__ B1,
              const float* __restrict__ Wt2, const float* __restrict__ B2,
              float* __restrict__ out)
{
#pragma clang fp contract(off)
    __shared__ __align__(16) char smem[16640];
    const int tid = threadIdx.x, lane = tid & 63;
    if ((int)blockIdx.x < BATCH) {
        // ---------------- FPS stage 2 ----------------
        constexpr int P2 = NP1 / BLOCK;
        constexpr int NW = BLOCK / 64;
        float* s2x = (float*)smem;                 // [NP1]
        float* s2y = s2x + NP1;
        float* s2z = s2y + NP1;
        float* o2x = s2z + NP1;                    // [NP2]
        float* o2y = o2x + NP2;
        float* o2z = o2y + NP2;
        unsigned long long* wslot = (unsigned long long*)(o2z + NP2); // [2][NW]
        const int b = blockIdx.x, t = tid, wv = t >> 6;
        const float* l1b = l1xyz + (size_t)b * NP1 * 3;
        float mx[P2], my[P2], mz[P2], d2[P2];
#pragma unroll
        for (int j = 0; j < P2; ++j) {
            const int i = t + j * BLOCK;
            const float x = l1b[i*3+0], y = l1b[i*3+1], z = l1b[i*3+2];
            s2x[i] = x; s2y[i] = y; s2z[i] = z;
            mx[j] = x; my[j] = y; mz[j] = z;
            d2[j] = 1e10f;
        }
        __syncthreads();
        float fx = s2x[0], fy = s2y[0], fz = s2z[0];
        if (t == 0) { o2x[0] = fx; o2y[0] = fy; o2z[0] = fz; }
        for (int s = 1; s < NP2; ++s) {
            float bestv = -1.f; int besti = 0;
#pragma unroll
            for (int j = 0; j < P2; ++j) {
                const float dx = mx[j]-fx, dy = my[j]-fy, dz = mz[j]-fz;
                const float d = (dx*dx + dy*dy) + dz*dz;
                const float nd = fminf(d2[j], d);
                d2[j] = nd;
                if (nd > bestv) { bestv = nd; besti = t + j * BLOCK; }
            }
            const float wm = wave_max_bcast(bestv);
            const unsigned cand = (bestv == wm) ? (unsigned)besti : 0xffffffffu;
            const unsigned wi = wave_min_bcast(cand);
            const int par = s & 1;
            if (lane == 0)
                wslot[par*NW + wv] = ((unsigned long long)__float_as_uint(wm) << 32)
                                   | (unsigned)(~wi);
            __syncthreads();
            unsigned long long pa = wslot[par*NW + 0];
#pragma unroll
            for (int w = 1; w < NW; ++w) {
                const unsigned long long pb = wslot[par*NW + w];
                pa = (pb > pa) ? pb : pa;
            }
            const int far2 = (int)(~(unsigned)pa);
            fx = s2x[far2]; fy = s2y[far2]; fz = s2z[far2];
            if (t == 0) { o2x[s] = fx; o2y[s] = fy; o2z[s] = fz; }
        }
        __syncthreads();
        for (int i = t; i < NP2; i += BLOCK) {
            out2[((size_t)b*NP2 + i)*3 + 0] = o2x[i];
            out2[((size_t)b*NP2 + i)*3 + 1] = o2y[i];
            out2[((size_t)b*NP2 + i)*3 + 2] = o2z[i];
        }
        return;
    }
    // ---------------- SA1 (+inline ball query) ----------------
    float (*buf)[64] = (float(*)[64])smem;         // [64][64]
    int* sidx = (int*)(smem + 16384);              // [64]
    const int wave = __builtin_amdgcn_readfirstlane(tid >> 6);
    const int row0 = (blockIdx.x - BATCH) * 64;
    const int g0 = row0 >> 5;
    const int b = g0 >> 9;
    const float* xb = xyz + (size_t)b * 4096 * 3;
    if (wave < 2) {
        const int g = g0 + wave;
        ballq_scan_lds<4096, 32>(xb,
            l1xyz[(size_t)g*3 + 0], l1xyz[(size_t)g*3 + 1], l1xyz[(size_t)g*3 + 2],
            r2, sidx + wave*32, lane);
    }
    __syncthreads();
    const int g = g0 + (lane >> 5);
    const int i = sidx[lane];
    const float* p = xb + (size_t)i * 3;
    const float f0 = p[0] - l1xyz[(size_t)g*3 + 0];
    const float f1 = p[1] - l1xyz[(size_t)g*3 + 1];
    const float f2 = p[2] - l1xyz[(size_t)g*3 + 2];
    const int oc0 = wave * 16;
    f32x2 aL[8], aH[8];
#pragma unroll
    for (int j = 0; j < 16; ++j) {
        const float v = B0[oc0+j] + f0*Wt0[0*64+oc0+j] + f1*Wt0[1*64+oc0+j] + f2*Wt0[2*64+oc0+j];
        buf[oc0+j][lane] = fmaxf(v, 0.f);
    }
    __syncthreads();
#pragma unroll
    for (int k = 0; k < 8; ++k) aL[k] = mk2(B1[oc0+2*k], B1[oc0+2*k+1]);
#pragma unroll 4
    for (int ci = 0; ci < 64; ++ci)
        fma16pk(aL, buf[ci][lane], Wt1 + ci*64 + oc0);
    __syncthreads();
#pragma unroll
    for (int k = 0; k < 8; ++k) {
        buf[oc0+2*k][lane]   = fmaxf(aL[k].x, 0.f);
        buf[oc0+2*k+1][lane] = fmaxf(aL[k].y, 0.f);
    }
    __syncthreads();
#pragma unroll
    for (int k = 0; k < 8; ++k) {
        aL[k] = mk2(B2[oc0+2*k], B2[oc0+2*k+1]);
        aH[k] = mk2(B2[64+oc0+2*k], B2[64+oc0+2*k+1]);
    }
#pragma unroll 2
    for (int ci = 0; ci < 64; ++ci) {
        const float f = buf[ci][lane];
        fma16pk(aL, f, Wt2 + ci*128 + oc0);
        fma16pk(aH, f, Wt2 + ci*128 + 64 + oc0);
    }
#pragma unroll
    for (int k = 0; k < 8; ++k) {
        const float v0 = pool_half(fmaxf(aL[k].x, 0.f));
        const float v1 = pool_half(fmaxf(aL[k].y, 0.f));
        const float w0 = pool_half(fmaxf(aH[k].x, 0.f));
        const float w1 = pool_half(fmaxf(aH[k].y, 0.f));
        if ((lane & 31) == 0) {
            const size_t orow = (size_t)((row0 + lane) >> 5) * 128;
            out[orow + oc0 + 2*k]       = v0;
            out[orow + oc0 + 2*k + 1]   = v1;
            out[orow + 64 + oc0 + 2*k]     = w0;
            out[orow + 64 + oc0 + 2*k + 1] = w1;
        }
    }
}

// ---------------------------------------------------------------------------
// SA2 fused + inline ball query + SA3-L1 + SA3-L2 epilogues. (unchanged R15)
// ---------------------------------------------------------------------------
__global__ __launch_bounds__(256)
void sa2_fused(const float* __restrict__ l1xyz, const float* __restrict__ l1pts,
               const float* __restrict__ nxyz, const float r2,
               const float* __restrict__ Wt0, const float* __restrict__ B0,
               const float* __restrict__ Wt1, const float* __restrict__ B1,
               const float* __restrict__ Wt2, const float* __restrict__ B2,
               const float* __restrict__ Wt30, const float* __restrict__ B30,
               const float* __restrict__ Wt31, const float* __restrict__ B31,
               float* __restrict__ outH2)
{
    __shared__ float buf[128][64];
    __shared__ float pool[256];
    __shared__ float h1s[256];
    __shared__ int sidx[64];
    const int tid = threadIdx.x, lane = tid & 63;
    const int wave = __builtin_amdgcn_readfirstlane(tid >> 6);
    const int gblk = blockIdx.x;
    const int b = gblk >> 7;
    const float cx = nxyz[(size_t)gblk*3 + 0];
    const float cy = nxyz[(size_t)gblk*3 + 1];
    const float cz = nxyz[(size_t)gblk*3 + 2];
    const float* xb = l1xyz + (size_t)b * 512 * 3;
    if (wave == 0)
        ballq_scan_lds<512, 64>(xb, cx, cy, cz, r2, sidx, lane);
    __syncthreads();
    const int myi = sidx[lane];
    const float* pc = xb + (size_t)myi * 3;
    const float f0 = pc[0] - cx;
    const float f1 = pc[1] - cy;
    const float f2 = pc[2] - cz;
    for (int r = wave; r < 64; r += 4) {
        const int i2 = sidx[r];
        const float* src = l1pts + ((size_t)b*512 + i2) * 128;
        buf[lane][r ^ lane]    = src[lane];
        buf[lane+64][r ^ lane] = src[lane + 64];
    }
    __syncthreads();
    const int oc0 = wave * 16;
    f32x2 aL[8], aH[8];
#pragma unroll
    for (int k = 0; k < 8; ++k) {
        const int j0 = oc0 + 2*k, j1 = oc0 + 2*k + 1;
        aL[k] = mk2(B0[j0]    + f0*Wt0[j0]     + f1*Wt0[128+j0]    + f2*Wt0[256+j0],
                    B0[j1]    + f0*Wt0[j1]     + f1*Wt0[128+j1]    + f2*Wt0[256+j1]);
        aH[k] = mk2(B0[64+j0] + f0*Wt0[64+j0]  + f1*Wt0[192+j0]    + f2*Wt0[320+j0],
                    B0[64+j1] + f0*Wt0[64+j1]  + f1*Wt0[192+j1]    + f2*Wt0[320+j1]);
    }
#pragma unroll 2
    for (int ci = 0; ci < 128; ++ci) {
        const float f = buf[ci][lane ^ (ci & 63)];
        const float* wp = Wt0 + (size_t)(ci+3)*128;
        fma16pk(aL, f, wp + oc0);
        fma16pk(aH, f, wp + 64 + oc0);
    }
    __syncthreads();
#pragma unroll
    for (int k = 0; k < 8; ++k) {
        buf[oc0+2*k][lane]      = fmaxf(aL[k].x, 0.f);
        buf[oc0+2*k+1][lane]    = fmaxf(aL[k].y, 0.f);
        buf[64+oc0+2*k][lane]   = fmaxf(aH[k].x, 0.f);
        buf[64+oc0+2*k+1][lane] = fmaxf(aH[k].y, 0.f);
    }
    __syncthreads();
#pragma unroll
    for (int k = 0; k < 8; ++k) {
        aL[k] = mk2(B1[oc0+2*k], B1[oc0+2*k+1]);
        aH[k] = mk2(B1[64+oc0+2*k], B1[64+oc0+2*k+1]);
    }
#pragma unroll 2
    for (int ci = 0; ci < 128; ++ci) {
        const float f = buf[ci][lane];
        const float* wp = Wt1 + (size_t)ci*128;
        fma16pk(aL, f, wp + oc0);
        fma16pk(aH, f, wp + 64 + oc0);
    }
    __syncthreads();
#pragma unroll
    for (int k = 0; k < 8; ++k) {
        buf[oc0+2*k][lane]      = fmaxf(aL[k].x, 0.f);
        buf[oc0+2*k+1][lane]    = fmaxf(aL[k].y, 0.f);
        buf[64+oc0+2*k][lane]   = fmaxf(aH[k].x, 0.f);
        buf[64+oc0+2*k+1][lane] = fmaxf(aH[k].y, 0.f);
    }
    __syncthreads();
    for (int half = 0; half < 2; ++half) {
        const int oc = half*128 + oc0;
#pragma unroll
        for (int k = 0; k < 8; ++k) {
            aL[k] = mk2(B2[oc+2*k], B2[oc+2*k+1]);
            aH[k] = mk2(B2[64+oc+2*k], B2[64+oc+2*k+1]);
        }
#pragma unroll 2
        for (int ci = 0; ci < 128; ++ci) {
            const float f = buf[ci][lane];
            const float* wp = Wt2 + (size_t)ci*256;
            fma16pk(aL, f, wp + oc);
            fma16pk(aH, f, wp + 64 + oc);
        }
#pragma unroll
        for (int k = 0; k < 8; ++k) {
            const float v0 = pool_full(fmaxf(aL[k].x, 0.f));
            const float v1 = pool_full(fmaxf(aL[k].y, 0.f));
            const float w0 = pool_full(fmaxf(aH[k].x, 0.f));
            const float w1 = pool_full(fmaxf(aH[k].y, 0.f));
            if (lane == 0) {
                pool[oc + 2*k]        = v0;
                pool[oc + 2*k + 1]    = v1;
                pool[64 + oc + 2*k]   = w0;
                pool[64 + oc + 2*k+1] = w1;
            }
        }
    }
    __syncthreads();
    {
        float acc = B30[tid] + cx*Wt30[0*256+tid] + cy*Wt30[1*256+tid] + cz*Wt30[2*256+tid];
#pragma unroll 8
        for (int ci = 0; ci < 256; ++ci)
            acc += pool[ci] * Wt30[(size_t)(ci+3)*256 + tid];
        h1s[tid] = fmaxf(acc, 0.f);
    }
    __syncthreads();
    {
        float a0 = B31[tid], a1 = B31[256 + tid];
#pragma unroll 8
        for (int ci = 0; ci < 256; ++ci) {
            const float f = h1s[ci];
            a0 += f * Wt31[(size_t)ci*512 + tid];
            a1 += f * Wt31[(size_t)ci*512 + 256 + tid];
        }
        outH2[(size_t)gblk*512 + tid]       = fmaxf(a0, 0.f);
        outH2[(size_t)gblk*512 + 256 + tid] = fmaxf(a1, 0.f);
    }
}

// ---------------------------------------------------------------------------
// SA3 GEMM layer (<512,1024,POOL>), packed-FMA accumulators. (unchanged)
// ---------------------------------------------------------------------------
template<int CIN, int COUT, bool CONCAT3, bool POOL>
__global__ __launch_bounds__(256)
void mlp_gemm_kernel(const float* __restrict__ inA, const float* __restrict__ inB,
                     const float* __restrict__ Wt, const float* __restrict__ Bb,
                     float* __restrict__ out)
{
    __shared__ float featS[128][64];
    const int tid = threadIdx.x, lane = tid & 63;
    const int wave = __builtin_amdgcn_readfirstlane(tid >> 6);
    const int row0 = blockIdx.x * 64;
    const int oc0 = blockIdx.y * 64 + wave * 16;
    f32x2 acc[8];
#pragma unroll
    for (int k = 0; k < 8; ++k) acc[k] = mk2(Bb[oc0+2*k], Bb[oc0+2*k+1]);
    for (int c0 = 0; c0 < CIN; c0 += 128) {
        const int csz = (CIN - c0 < 128) ? (CIN - c0) : 128;
        __syncthreads();
        for (int r = wave; r < 64; r += 4) {
            const int row = row0 + r;
            for (int cl = lane; cl < csz; cl += 64) {
                const int cig = c0 + cl;
                float v;
                if (CONCAT3)
                    v = (cig < 3) ? inA[(size_t)row*3 + cig]
                                  : inB[(size_t)row*(CIN-3) + (cig - 3)];
                else
                    v = inA[(size_t)row*CIN + cig];
                featS[cl][r ^ (cl & 63)] = v;
            }
        }
        __syncthreads();
        if (csz == 128) {
#pragma unroll 4
            for (int ci = 0; ci < 128; ++ci)
                fma16pk(acc, featS[ci][lane ^ (ci & 63)], Wt + (size_t)(c0+ci)*COUT + oc0);
        } else {
            for (int ci = 0; ci < csz; ++ci)
                fma16pk(acc, featS[ci][lane ^ (ci & 63)], Wt + (size_t)(c0+ci)*COUT + oc0);
        }
    }
    if (POOL) {
#pragma unroll
        for (int k = 0; k < 8; ++k) {
            const float v0 = pool_full(fmaxf(acc[k].x, 0.f));
            const float v1 = pool_full(fmaxf(acc[k].y, 0.f));
            if (lane == 0) {
                out[(size_t)blockIdx.x * COUT + oc0 + 2*k]     = v0;
                out[(size_t)blockIdx.x * COUT + oc0 + 2*k + 1] = v1;
            }
        }
    } else {
        float4 o0, o1, o2, o3;
        o0.x=fmaxf(acc[0].x,0.f); o0.y=fmaxf(acc[0].y,0.f); o0.z=fmaxf(acc[1].x,0.f); o0.w=fmaxf(acc[1].y,0.f);
        o1.x=fmaxf(acc[2].x,0.f); o1.y=fmaxf(acc[2].y,0.f); o1.z=fmaxf(acc[3].x,0.f); o1.w=fmaxf(acc[3].y,0.f);
        o2.x=fmaxf(acc[4].x,0.f); o2.y=fmaxf(acc[4].y,0.f); o2.z=fmaxf(acc[5].x,0.f); o2.w=fmaxf(acc[5].y,0.f);
        o3.x=fmaxf(acc[6].x,0.f); o3.y=fmaxf(acc[6].y,0.f); o3.z=fmaxf(acc[7].x,0.f); o3.w=fmaxf(acc[7].y,0.f);
        float4* op = (float4*)(out + (size_t)(row0 + lane)*COUT + oc0);
        op[0]=o0; op[1]=o1; op[2]=o2; op[3]=o3;
    }
}

// y[b][o] = fb[o] + max(pmax[2b], pmax[2b+1]) . fw[o]; one wave per output
__global__ __launch_bounds__(256)
void fc_kernel(const float* __restrict__ pmax, const float* __restrict__ fw,
               const float* __restrict__ fb, float* __restrict__ y)
{
    const int gw = (blockIdx.x * 256 + threadIdx.x) >> 6;
    const int lane = threadIdx.x & 63;
    const int b = gw >> 10, o = gw & 1023;
    const float4* g0 = (const float4*)(pmax + (size_t)(2*b) * 1024);
    const float4* g1 = (const float4*)(pmax + (size_t)(2*b+1) * 1024);
    const float4* wv = (const float4*)(fw + (size_t)o * 1024);
    float acc = 0.f;
#pragma unroll
    for (int r = 0; r < 4; ++r) {
        const float4 a = g0[lane + r*64];
        const float4 c = g1[lane + r*64];
        const float4 w = wv[lane + r*64];
        acc += fmaxf(a.x,c.x)*w.x + fmaxf(a.y,c.y)*w.y
             + fmaxf(a.z,c.z)*w.z + fmaxf(a.w,c.w)*w.w;
    }
#pragma unroll
    for (int m = 32; m >= 1; m >>= 1) acc += __shfl_xor(acc, m);
    if (lane == 0) y[gw] = acc + fb[o];
}

extern "C" void kernel_launch(void* const* d_in, const int* in_sizes, int n_in,
                              void* d_out, int out_size, void* d_ws, size_t ws_size,
                              hipStream_t stream)
{
    (void)in_sizes; (void)n_in; (void)out_size; (void)ws_size;
    const float* x   = (const float*)d_in[0];
    const float* s1w0 = (const float*)d_in[1];  const float* s1b0 = (const float*)d_in[2];
    const float* s1w1 = (const float*)d_in[3];  const float* s1b1 = (const float*)d_in[4];
    const float* s1w2 = (const float*)d_in[5];  const float* s1b2 = (const float*)d_in[6];
    const float* s2w0 = (const float*)d_in[7];  const float* s2b0 = (const float*)d_in[8];
    const float* s2w1 = (const float*)d_in[9];  const float* s2b1 = (const float*)d_in[10];
    const float* s2w2 = (const float*)d_in[11]; const float* s2b2 = (const float*)d_in[12];
    const float* s3w0 = (const float*)d_in[13]; const float* s3b0 = (const float*)d_in[14];
    const float* s3w1 = (const float*)d_in[15]; const float* s3b1 = (const float*)d_in[16];
    const float* s3w2 = (const float*)d_in[17]; const float* s3b2 = (const float*)d_in[18];
    const float* fw  = (const float*)d_in[19]; const float* fb  = (const float*)d_in[20];
    float* y = (float*)d_out;

    char* ws = (char*)d_ws;
    float* l1_xyz = (float*)(ws + 0);          // 16*512*3
    float* l1_pts = (float*)(ws + 1146880);    // 16*512*128
    float* l2_xyz = (float*)(ws + 5341184);    // 16*128*3
    float* h2     = (float*)(ws + 10084352);   // 2048*512
    float* pmax   = (float*)(ws + 14278656);   // 32*1024 partial maxes
    float* wt1_0  = (float*)(ws + 14409728);   // [3][64]
    float* wt1_1  = (float*)(ws + 14410496);   // [64][64]
    float* wt1_2  = (float*)(ws + 14426880);   // [64][128]
    float* wt2_0  = (float*)(ws + 14459648);   // [131][128]
    float* wt2_1  = (float*)(ws + 14526720);   // [128][128]
    float* wt2_2  = (float*)(ws + 14592256);   // [128][256]
    float* wt3_0  = (float*)(ws + 14723328);   // [259][256]
    float* wt3_1  = (float*)(ws + 14988544);   // [256][512]
    float* wt3_2  = (float*)(ws + 15512832);   // [512][1024]

    const float r2_1 = (float)(0.2 * 0.2);
    const float r2_2 = (float)(0.4 * 0.4);

    // K1: FPS stage 1 (16 blocks) + all weight transposes (3126 blocks)
    fps1_fused<4096, 512, 256><<<BATCH + 3126, 256, 0, stream>>>(
        x, l1_xyz,
        s1w0, wt1_0, s1w1, wt1_1, s1w2, wt1_2,
        s2w0, wt2_0, s2w1, wt2_1, s2w2, wt2_2,
        s3w0, wt3_0, s3w1, wt3_1, s3w2, wt3_2);
    // K2: FPS stage 2 (16 blocks) runs CONCURRENTLY with SA1 (4096 blocks)
    fps2_sa1<512, 128, 256><<<BATCH + (BATCH*512*32)/64, 256, 0, stream>>>(
        x, l1_xyz, l2_xyz, r2_1,
        wt1_0, s1b0, wt1_1, s1b1, wt1_2, s1b2, l1_pts);
    sa2_fused<<<BATCH*128, 256, 0, stream>>>(l1_xyz, l1_pts, l2_xyz, r2_2,
        wt2_0, s2b0, wt2_1, s2b1, wt2_2, s2b2,
        wt3_0, s3b0, wt3_1, s3b1, h2);
    mlp_gemm_kernel<512, 1024, false, true ><<<dim3(32, 16), 256, 0, stream>>>(h2, nullptr, wt3_2, s3b2, pmax);
    fc_kernel<<<(BATCH*1024)/4, 256, 0, stream>>>(pmax, fw, fb, y);
}